// Round 4
// baseline (1636.325 us; speedup 1.0000x reference)
//
#include <hip/hip_runtime.h>

// ---------------------------------------------------------------------------
// BiLSTM-CRF forward loss on MI355X (gfx950).
// R11: R10 (correct, fused, but contention-slow) + spin-throttling via
// slab-ready counters + 2x producer parallelism.
//   - lstm waves publish progress: atomicAdd(prog[dir][s]) after h-store
//     (fire-and-forget). Slab s ready when count==256 (64 blocks x 4 waves).
//   - gemm producers / heads blocks gate each K-half on the counters with a
//     single-lane, s_sleep-backoff poll (1 load/1024cy) instead of 2048-line
//     atomic spin sweeps -> no more mall contention with the h handoff.
//   - post-flag A staging: one atomic u64 sweep + sentinel-retry backstop.
//   - phase0 grid 384: 128 lstm + 256 producers (4 tiles each, middle-out).
// Chain: memsets -> prep -> bert GEMM -> gates0 GEMM
//   -> COOP A (384): lstm L0 + gates1 producers -> COOP B (160): lstm L1 +
//      heads -> CRF.  !bigws fallback = R7 serial GEMMs.
// ---------------------------------------------------------------------------

typedef unsigned short u16;
typedef unsigned int u32;
typedef unsigned long long u64;
typedef __attribute__((ext_vector_type(8))) __bf16 bf16x8;
typedef __attribute__((ext_vector_type(4))) float floatx4;

static __device__ __forceinline__ u16 f2bf(float f) {
  u32 u = __float_as_uint(f);
  u += 0x7fffu + ((u >> 16) & 1u);   // round-to-nearest-even
  return (u16)(u >> 16);
}
static __device__ __forceinline__ float bf2f(u32 bits) {
  return __uint_as_float(bits << 16);
}
static __device__ __forceinline__ float sigf(float x) {
  return 1.0f / (1.0f + __expf(-x));
}
static __device__ __forceinline__ float tanh_(float x) {
  return 1.0f - 2.0f / (1.0f + __expf(2.0f * x));
}
static __device__ __forceinline__ floatx4 mfma16(bf16x8 a, bf16x8 b, floatx4 c) {
  return __builtin_amdgcn_mfma_f32_16x16x32_bf16(a, b, c, 0, 0, 0);
}
static __device__ __forceinline__ u64 aload64(const u64* p) {
  return __hip_atomic_load((u64*)p, __ATOMIC_RELAXED, __HIP_MEMORY_SCOPE_AGENT);
}
static __device__ __forceinline__ void astore64(u64* p, u64 v) {
  __hip_atomic_store(p, v, __ATOMIC_RELAXED, __HIP_MEMORY_SCOPE_AGENT);
}
static __device__ __forceinline__ u32 aload32(const u32* p) {
  return __hip_atomic_load((u32*)p, __ATOMIC_RELAXED, __HIP_MEMORY_SCOPE_AGENT);
}

// ---------------------------------------------------------------------------
// prep: fp32->bf16 conversions + bias sums + zero d_out
// ---------------------------------------------------------------------------
__global__ __launch_bounds__(256) void prep_kernel(
    const float* __restrict__ w_ih, const float* __restrict__ w_hh,
    const float* __restrict__ b_ih, const float* __restrict__ b_hh,
    const float* __restrict__ src,  const float* __restrict__ bert,
    const float* __restrict__ hwp,  const float* __restrict__ hbp,
    const float* __restrict__ hwm,  const float* __restrict__ hbm,
    u16* __restrict__ Wsrc, u16* __restrict__ Wbert, u16* __restrict__ Wih1,
    u16* __restrict__ Whh,  u16* __restrict__ SrcBf, u16* __restrict__ BertBf,
    u16* __restrict__ Wheads, float* __restrict__ b0sum, float* __restrict__ b1sum,
    float* __restrict__ hb, float* __restrict__ dout)
{
  const int NA = 4194304;  // w_ih layer0 -> Wsrc (cols 0:256) + Wbert (256:1024)
  const int NB = 4194304;  // w_ih layer1
  const int NC = 4194304;  // w_hh (both layers)
  const int ND = 1048576;  // src
  const int NE = 24576;    // bert
  const int NF = 98304;    // head weights
  const int NG = 8192;     // bias sums
  const int NH = 96;       // head bias
  const int TOTAL = NA + NB + NC + ND + NE + NF + NG + NH + 1;
  for (int i = blockIdx.x * 256 + threadIdx.x; i < TOTAL; i += gridDim.x * 256) {
    int x = i;
    if (x < NA) {
      int c = x & 1023, r = x >> 10;          // r = dir*2048 + row
      float v = w_ih[x];
      if (c < 256) Wsrc[r * 256 + c] = f2bf(v);
      else         Wbert[r * 768 + (c - 256)] = f2bf(v);
      continue;
    }
    x -= NA;
    if (x < NB) { Wih1[x] = f2bf(w_ih[NA + x]); continue; }
    x -= NB;
    if (x < NC) { Whh[x] = f2bf(w_hh[x]); continue; }
    x -= NC;
    if (x < ND) { SrcBf[x] = f2bf(src[x]); continue; }
    x -= ND;
    if (x < NE) { BertBf[x] = f2bf(bert[x]); continue; }
    x -= NE;
    if (x < NF) {
      Wheads[x] = f2bf(x < 32768 ? hwp[x] : hwm[x - 32768]);
      continue;
    }
    x -= NF;
    if (x < NG) {
      float v = b_ih[x] + b_hh[x];
      if (x < 4096) b0sum[x] = v; else b1sum[x - 4096] = v;
      continue;
    }
    x -= NG;
    if (x < NH) { hb[x] = (x < 32) ? hbp[x] : hbm[x - 32]; continue; }
    dout[0] = 0.f;
  }
}

// ---------------------------------------------------------------------------
// standalone bf16 NT GEMM (R7-exact): acc[m][n] = sum_k A[m][k]*B[n][k]
// (+bias[n]) (+aux[m%32][n]). 128x128 tile, BK=64, XOR-swizzled LDS.
// mode 0: C fp32. mode 1: bf16 gates, wave-ordered u64 layout.
// ---------------------------------------------------------------------------
__global__ __launch_bounds__(256) void gemm_nt(
    const u16* __restrict__ A, int lda,
    const u16* __restrict__ B, int ldb,
    float* __restrict__ C, int ldc,
    int M, int N, int K,
    const float* __restrict__ bias_n,
    const float* __restrict__ auxBN, int auxld,
    int mode)
{
  __shared__ __align__(16) u16 As[128 * 64];
  __shared__ __align__(16) u16 Bs[128 * 64];
  const int m0 = blockIdx.y * 128, n0 = blockIdx.x * 128;
  const int tid = threadIdx.x;
  const int wv = tid >> 6, ln = tid & 63;
  const int wm = wv & 1, wn = wv >> 1;
  const int q = ln >> 4, l15 = ln & 15;
  floatx4 acc[4][4];
#pragma unroll
  for (int a = 0; a < 4; ++a)
#pragma unroll
    for (int b2 = 0; b2 < 4; ++b2) acc[a][b2] = (floatx4){0.f, 0.f, 0.f, 0.f};

  for (int kk = 0; kk < K; kk += 64) {
    __syncthreads();
#pragma unroll
    for (int j = 0; j < 4; ++j) {
      const int idx = j * 256 + tid;   // 1024 16B chunks per operand tile
      const int r = idx >> 3, cc = idx & 7;
      const int slot = cc ^ (r & 7);
      const int ra = min(m0 + r, M - 1);
      *(int4*)&As[r * 64 + slot * 8] = *(const int4*)&A[(long)ra * lda + kk + cc * 8];
      const int rb = min(n0 + r, N - 1);
      *(int4*)&Bs[r * 64 + slot * 8] = *(const int4*)&B[(long)rb * ldb + kk + cc * 8];
    }
    __syncthreads();
#pragma unroll
    for (int ks = 0; ks < 2; ++ks) {
      bf16x8 af[4], bf[4];
#pragma unroll
      for (int im = 0; im < 4; ++im) {
        const int r = wm * 64 + im * 16 + l15;
        const int slot = (ks * 4 + q) ^ (r & 7);
        af[im] = *(const bf16x8*)&As[r * 64 + slot * 8];
      }
#pragma unroll
      for (int jn = 0; jn < 4; ++jn) {
        const int r = wn * 64 + jn * 16 + l15;
        const int slot = (ks * 4 + q) ^ (r & 7);
        bf[jn] = *(const bf16x8*)&Bs[r * 64 + slot * 8];
      }
#pragma unroll
      for (int im = 0; im < 4; ++im)
#pragma unroll
        for (int jn = 0; jn < 4; ++jn)
          acc[im][jn] = mfma16(af[im], bf[jn], acc[im][jn]);
    }
  }
  // epilogue: C/D layout col=lane&15, row=(lane>>4)*4+reg
  if (mode == 0) {
#pragma unroll
    for (int im = 0; im < 4; ++im)
#pragma unroll
      for (int jn = 0; jn < 4; ++jn) {
        const int n = n0 + wn * 64 + jn * 16 + l15;
        if (n < N) {
          const float badd = bias_n ? bias_n[n] : 0.f;
#pragma unroll
          for (int rg = 0; rg < 4; ++rg) {
            const int m = m0 + wm * 64 + im * 16 + q * 4 + rg;
            if (m < M) {
              float v = acc[im][jn][rg] + badd;
              if (auxBN) v += auxBN[(long)(m & 31) * auxld + n];
              C[(long)m * ldc + n] = v;
            }
          }
        }
      }
  } else {
    u64* G = (u64*)C;
#pragma unroll
    for (int im = 0; im < 4; ++im)
#pragma unroll
      for (int jn = 0; jn < 4; ++jn) {
        const int n = n0 + wn * 64 + jn * 16 + l15;
        const int dirsel = n >> 11, nn = n & 2047;
        const int gt = nn >> 9, u = nn & 511;
        const int ub = u >> 4, low = u & 15;
        const int wvl = low >> 2, jl = low & 3;
        const int l15l = gt * 4 + jl;
        const int m = m0 + wm * 64 + im * 16 + q * 4;   // rg=0 row
        const int s = m >> 5, b0 = m & 31;
        const int mh = b0 >> 4, qq = (b0 >> 2) & 3;
        const float badd = bias_n ? bias_n[n] : 0.f;
        u64 pk = 0;
#pragma unroll
        for (int rg = 0; rg < 4; ++rg) {
          float v = acc[im][jn][rg] + badd;
          if (auxBN) v += auxBN[(long)(b0 + rg) * auxld + n];
          pk |= (u64)f2bf(v) << (16 * rg);
        }
        G[(((((long)dirsel * 128 + s) * 2 + mh) * 32 + ub) * 4 + wvl) * 64
          + l15l * 4 + qq] = pk;
      }
  }
}

// ---------------------------------------------------------------------------
// fused GEMM tile: one 128x128 output tile; spinA=1 stages A rows produced
// concurrently by lstm blocks. Readiness gated on slab counters (prog), then
// one atomic u64 sweep + sentinel-retry backstop.
// mode 0: fp32 C. mode 1: wave-ordered bf16 gate u64, plain store.
// ---------------------------------------------------------------------------
static __device__ void gemm_tile(
    const u16* __restrict__ A, int lda,
    const u16* __restrict__ B, int ldb,
    float* __restrict__ C, int ldc,
    int m0, int n0, int M, int N, int K,
    const float* __restrict__ bias_n,
    int mode, int spinA, const u32* __restrict__ prog, u16* smem)
{
  u16* As = smem;             // [128*64]
  u16* Bs = smem + 128 * 64;  // [128*64]
  const int tid = threadIdx.x;
  const int wv = tid >> 6, ln = tid & 63;
  const int wm = wv & 1, wn = wv >> 1;
  const int q = ln >> 4, l15 = ln & 15;
  floatx4 acc[4][4];
#pragma unroll
  for (int a = 0; a < 4; ++a)
#pragma unroll
    for (int b2 = 0; b2 < 4; ++b2) acc[a][b2] = (floatx4){0.f, 0.f, 0.f, 0.f};

  for (int kk = 0; kk < K; kk += 64) {
    __syncthreads();
    if (spinA && (kk == 0 || kk == 512)) {
      // gate this K-half on the producing direction's slab counters.
      // single-lane low-rate poll: no mall contention with the h handoff.
      if (tid == 0) {
        const int dsel = kk >> 9;
        const int s0 = m0 >> 5;
        for (int i = 0; i < 4; ++i)
          while (aload32(&prog[dsel * 128 + s0 + i]) < 256u)
            __builtin_amdgcn_s_sleep(16);
      }
      __syncthreads();
    }
    if (spinA) {
      // A rows are lstm h outputs: one coalesced atomic sweep (data is ready
      // per the counters); sentinel retry kept as a relaxed-ordering backstop.
      u64 va[8];
#pragma unroll
      for (int j = 0; j < 8; ++j) {
        const int idx = j * 256 + tid;
        const int r = idx >> 4, cc = idx & 15;
        va[j] = aload64((const u64*)&A[(long)(m0 + r) * lda + kk + cc * 4]);
      }
      while (true) {
        bool bad = false;
#pragma unroll
        for (int j = 0; j < 8; ++j) bad |= ((va[j] & 0xffffULL) == 0xffffULL);
        if (!bad) break;
        __builtin_amdgcn_s_sleep(8);
#pragma unroll
        for (int j = 0; j < 8; ++j)
          if ((va[j] & 0xffffULL) == 0xffffULL) {
            const int idx = j * 256 + tid;
            const int r = idx >> 4, cc = idx & 15;
            va[j] = aload64((const u64*)&A[(long)(m0 + r) * lda + kk + cc * 4]);
          }
      }
#pragma unroll
      for (int j = 0; j < 8; ++j) {
        const int idx = j * 256 + tid;
        const int r = idx >> 4, cc = idx & 15;
        const int ch = cc >> 1, hf = cc & 1;
        *(u64*)&As[r * 64 + ((ch ^ (r & 7)) << 3) + (hf << 2)] = va[j];
      }
    } else {
#pragma unroll
      for (int j = 0; j < 4; ++j) {
        const int idx = j * 256 + tid;
        const int r = idx >> 3, cc = idx & 7;
        const int slot = cc ^ (r & 7);
        const int ra = min(m0 + r, M - 1);
        *(int4*)&As[r * 64 + slot * 8] = *(const int4*)&A[(long)ra * lda + kk + cc * 8];
      }
    }
#pragma unroll
    for (int j = 0; j < 4; ++j) {
      const int idx = j * 256 + tid;
      const int r = idx >> 3, cc = idx & 7;
      const int slot = cc ^ (r & 7);
      const int rb = min(n0 + r, N - 1);
      *(int4*)&Bs[r * 64 + slot * 8] = *(const int4*)&B[(long)rb * ldb + kk + cc * 8];
    }
    __syncthreads();
#pragma unroll
    for (int ks = 0; ks < 2; ++ks) {
      bf16x8 af[4], bf[4];
#pragma unroll
      for (int im = 0; im < 4; ++im) {
        const int r = wm * 64 + im * 16 + l15;
        const int slot = (ks * 4 + q) ^ (r & 7);
        af[im] = *(const bf16x8*)&As[r * 64 + slot * 8];
      }
#pragma unroll
      for (int jn = 0; jn < 4; ++jn) {
        const int r = wn * 64 + jn * 16 + l15;
        const int slot = (ks * 4 + q) ^ (r & 7);
        bf[jn] = *(const bf16x8*)&Bs[r * 64 + slot * 8];
      }
#pragma unroll
      for (int im = 0; im < 4; ++im)
#pragma unroll
        for (int jn = 0; jn < 4; ++jn)
          acc[im][jn] = mfma16(af[im], bf[jn], acc[im][jn]);
    }
  }
  // epilogue: C/D layout col=lane&15, row=(lane>>4)*4+reg
  if (mode == 0) {
#pragma unroll
    for (int im = 0; im < 4; ++im)
#pragma unroll
      for (int jn = 0; jn < 4; ++jn) {
        const int n = n0 + wn * 64 + jn * 16 + l15;
        if (n < N) {
          const float badd = bias_n ? bias_n[n] : 0.f;
#pragma unroll
          for (int rg = 0; rg < 4; ++rg) {
            const int m = m0 + wm * 64 + im * 16 + q * 4 + rg;
            if (m < M) C[(long)m * ldc + n] = acc[im][jn][rg] + badd;
          }
        }
      }
  } else {
    u64* G = (u64*)C;
#pragma unroll
    for (int im = 0; im < 4; ++im)
#pragma unroll
      for (int jn = 0; jn < 4; ++jn) {
        const int n = n0 + wn * 64 + jn * 16 + l15;
        const int dirsel = n >> 11, nn = n & 2047;
        const int gt = nn >> 9, u = nn & 511;
        const int ub2 = u >> 4, low = u & 15;
        const int wvl = low >> 2, jl = low & 3;
        const int l15l = gt * 4 + jl;
        const int m = m0 + wm * 64 + im * 16 + q * 4;   // rg=0 row
        const int s = m >> 5, b0 = m & 31;
        const int mh2 = b0 >> 4, qq = (b0 >> 2) & 3;
        const float badd = bias_n ? bias_n[n] : 0.f;
        u64 pk = 0;
#pragma unroll
        for (int rg = 0; rg < 4; ++rg)
          pk |= (u64)f2bf(acc[im][jn][rg] + badd) << (16 * rg);
        G[(((((long)dirsel * 128 + s) * 2 + mh2) * 32 + ub2) * 4 + wvl) * 64
          + l15l * 4 + qq] = pk;
      }
  }
}

// ---------------------------------------------------------------------------
// LSTM recurrence body (R7 protocol + per-step slab-progress publication).
// block = (dir, batch-half of 16, 16 units). Gates read with plain loads.
// ---------------------------------------------------------------------------
static __device__ void lstm_body(const u16* __restrict__ gates,
                                 u16* __restrict__ out,
                                 const u16* __restrict__ whh,
                                 u32* __restrict__ prog,
                                 u16* h_lds, float* gscf)
{
  const int bid = blockIdx.x;
  const int dir = bid >> 6;
  const int mh = (bid >> 5) & 1;
  const int ub = bid & 31;
  const int u0 = ub * 16;
  const int tid = threadIdx.x;
  const int wv = tid >> 6;
  const int ln = tid & 63;
  const int q = ln >> 4, l15 = ln & 15;

  // gate row for this lane's B-frag column n=l15: (n>>2)=gate type, (n&3)=unit
  const int gate_r = (l15 >> 2) * 512 + u0 + wv * 4 + (l15 & 3);

  bf16x8 bfrag[16];
  {
    const u16* wp = whh + ((long)dir * 2048 + gate_r) * 512 + q * 8;
#pragma unroll
    for (int ks = 0; ks < 16; ++ks)
      bfrag[ks] = *(const bf16x8*)(wp + ks * 32);
  }

  float c = 0.f;                       // cell state for (b_glob, j_lane)
  const int b_glob = mh * 16 + l15;    // batch (update phase)

  // wave-ordered gate pointer: stride per s = 2*32*4*64 = 16384 u64
  const u64* gbase = (const u64*)gates
      + ((((long)dir * 128 * 2 + mh) * 32 + ub) * 4 + wv) * 64 + l15 * 4 + q;

  u64 gcur = gbase[(long)(dir ? 127 : 0) * 16384];
  u64 gnext = 0;

  for (int t = 0; t < 128; ++t) {
    const int s = dir ? (127 - t) : t;
    // gate prefetch for t+1: coalesced 512 B per wave, issued before staging
    if (t < 127) {
      const int sn = dir ? (126 - t) : (t + 1);
      gnext = gbase[(long)sn * 16384];
    }
    floatx4 acc = (floatx4){0.f, 0.f, 0.f, 0.f};
    if (t > 0) {
      // stage h(t-1): 16 rows x 512 cols bf16. Coalesced device-scope u64
      // loads; each u64 = one producer wave's atomic store -> check low u16.
      const int sp = dir ? (s + 1) : (s - 1);
      const u64* ubp = (const u64*)(out + (((long)sp * 32 + mh * 16) * 1024 + (long)dir * 512));
      u64 v8[8];
#pragma unroll
      for (int j = 0; j < 8; ++j) {
        const int idx = j * 256 + tid;           // 2048 u64 chunks
        const int r = idx >> 7, c4 = idx & 127;  // row, u64-within-row
        v8[j] = aload64(ubp + (long)r * 256 + c4);
      }
      while (true) {
        bool bad = false;
#pragma unroll
        for (int j = 0; j < 8; ++j) bad |= ((v8[j] & 0xffffULL) == 0xffffULL);
        if (!bad) break;
#pragma unroll
        for (int j = 0; j < 8; ++j) {
          if ((v8[j] & 0xffffULL) == 0xffffULL) {
            const int idx = j * 256 + tid;
            const int r = idx >> 7, c4 = idx & 127;
            v8[j] = aload64(ubp + (long)r * 256 + c4);
          }
        }
      }
#pragma unroll
      for (int j = 0; j < 8; ++j) {
        const int idx = j * 256 + tid;
        const int r = idx >> 7, c4 = idx & 127;
        const int cc8 = c4 >> 1, hf = c4 & 1;
        *(u64*)&h_lds[r * 512 + ((cc8 ^ (r & 7)) << 3) + (hf << 2)] = v8[j];
      }
      __syncthreads();   // the ONLY barrier per step
      floatx4 acc1 = (floatx4){0.f, 0.f, 0.f, 0.f};
#pragma unroll
      for (int ks = 0; ks < 16; ks += 2) {   // 2 chains to halve dep latency
        const int slot0 = (ks * 4 + q) ^ (l15 & 7);
        bf16x8 a0 = *(const bf16x8*)&h_lds[l15 * 512 + slot0 * 8];
        acc = mfma16(a0, bfrag[ks], acc);
        const int slot1 = ((ks + 1) * 4 + q) ^ (l15 & 7);
        bf16x8 a1 = *(const bf16x8*)&h_lds[l15 * 512 + slot1 * 8];
        acc1 = mfma16(a1, bfrag[ks + 1], acc1);
      }
      acc += acc1;
    }
    // C-frag (row=batch=q*4+rg, col=n=l15) -> wave-local LDS transpose
#pragma unroll
    for (int rg = 0; rg < 4; ++rg)
      gscf[(wv * 16 + q * 4 + rg) * 17 + l15] =
          acc[rg] + bf2f((u32)((gcur >> (16 * rg)) & 0xffffu));
    // gscf wave slice touched only by wave wv: wave-synchronous, no barrier
    const float gi = gscf[(wv * 16 + l15) * 17 + q];
    const float gf = gscf[(wv * 16 + l15) * 17 + 4 + q];
    const float gg = gscf[(wv * 16 + l15) * 17 + 8 + q];
    const float go = gscf[(wv * 16 + l15) * 17 + 12 + q];
    const float iv = sigf(gi), fv = sigf(gf), gv = tanh_(gg), ov = sigf(go);
    c = fv * c + iv * gv;
    const float h = ov * tanh_(c);
    // pack 4 units (quads q=0..3, lanes 16 apart) -> one u64 store by q==0
    const u32 hv = (u32)f2bf(h);
    const u32 p1 = (u32)__shfl_xor((int)hv, 16);
    const u32 lo32 = hv | (p1 << 16);
    const u64 w64 = (u64)lo32 |
                    ((u64)(u32)__shfl_xor((int)lo32, 32) << 32);
    if (q == 0)
      astore64((u64*)&out[((long)s * 32 + b_glob) * 1024 + dir * 512 + u0 + wv * 4], w64);
    // publish slab progress (fire-and-forget; 4 adds/block/step; consumers
    // gate on count==256 and keep the sentinel backstop for ordering)
    if (ln == 0)
      atomicAdd((u32*)&prog[dir * 128 + s], 1u);
    gcur = gnext;
  }
}

// ---------------------------------------------------------------------------
// fused cooperative kernel. 32 KiB LDS arena.
// phase 0 (grid 384): bid<128 lstm layer0 -> prog0; bid>=128: 4 gates1 tiles
//   middle-out into gatesOut, counter-gated A=out0.
// phase 1 (grid 160): bid<128 lstm layer1 -> prog1; bid 128..159 heads tiles.
// ---------------------------------------------------------------------------
__global__ __launch_bounds__(256, 1) void fused_lstm(
    int phase,
    const u16* __restrict__ gatesIn,
    u16* __restrict__ gatesOut,
    u16* __restrict__ outw,
    const u16* __restrict__ whh,
    const u16* __restrict__ Wih1, const float* __restrict__ b1sum,
    const u16* __restrict__ Wheads, const float* __restrict__ hb,
    float* __restrict__ feat,
    u32* __restrict__ prog)
{
  __shared__ __align__(16) u16 smem[16384];   // 32768 B (gemm uses all;
  const int bid = blockIdx.x;                 //  lstm carves 20736 B)
  if (bid < 128) {
    u16* h_lds = smem;                       // 16384 B
    float* gscf = (float*)(smem + 8192);     // 4352 B at byte 16384
    lstm_body(gatesIn, outw, whh, prog, h_lds, gscf);
  } else if (phase == 0) {
    const int g = bid - 128;                 // 0..255
    // gates1: out0 @ Wih1^T + b1sum -> gatesOut, middle-out M order
    for (int ord = 0; ord < 4; ++ord) {
      const int t = ord * 256 + g;
      const int k = t >> 5, cn = t & 31;
      const int rm = (k & 1) ? (16 + (k >> 1)) : (15 - (k >> 1));
      gemm_tile(outw, 1024, Wih1, 1024, (float*)gatesOut, 0,
                rm * 128, cn * 128, 4096, 4096, 1024,
                b1sum, 1, 1, prog, smem);
    }
  } else if (bid < 160) {
    const int g = bid - 128;                 // 0..31
    const int rm = (g & 1) ? (16 + (g >> 1)) : (15 - (g >> 1));
    gemm_tile(outw, 1024, Wheads, 1024, feat, 96,
              rm * 128, 0, 4096, 96, 1024,
              hb, 0, 1, prog, smem);
  }
}

// ---------------------------------------------------------------------------
// CRF: one block per (task, batch). Double-buffered alpha: 1 barrier/step.
// ---------------------------------------------------------------------------
template <int K>
static __device__ void crf_body(const float* __restrict__ feat, int off,
                                const int* __restrict__ labels, int b,
                                const float* __restrict__ start,
                                const float* __restrict__ end_,
                                const float* __restrict__ trans,
                                float* __restrict__ outp,
                                float* transT, float (*alpha)[64],
                                float* red)
{
  const int tid = threadIdx.x;
  for (int i = tid; i < K * K; i += 256) {
    int kk = i / K, kp2 = i % K;
    transT[kp2 * 65 + kk] = trans[i];
  }
  if (tid < K) alpha[0][tid] = start[tid] + feat[b * 96 + off + tid];
  __syncthreads();
  constexpr int Kq = K / 4;
  const int kp = tid >> 2, k4 = tid & 3;
  const bool act = kp < K;
  int p = 0;
  for (int s = 1; s < 128; ++s) {
    float x[Kq];
    float mx = -3e38f;
    if (act) {
      const float* tr = &transT[kp * 65 + k4 * Kq];
      const float* al = &alpha[p][k4 * Kq];
#pragma unroll
      for (int i2 = 0; i2 < Kq; ++i2) { x[i2] = al[i2] + tr[i2]; mx = fmaxf(mx, x[i2]); }
    }
    mx = fmaxf(mx, __shfl_xor(mx, 1));
    mx = fmaxf(mx, __shfl_xor(mx, 2));
    float ss = 0.f;
    if (act) {
#pragma unroll
      for (int i2 = 0; i2 < Kq; ++i2) ss += __expf(x[i2] - mx);
    }
    ss += __shfl_xor(ss, 1);
    ss += __shfl_xor(ss, 2);
    if (act && k4 == 0)
      alpha[p ^ 1][kp] = mx + __logf(ss) + feat[(s * 32 + b) * 96 + off + kp];
    __syncthreads();
    p ^= 1;
  }
  // numerator terms (one per time step)
  if (tid < 128) {
    const int tg = labels[tid * 32 + b];
    float term = feat[(tid * 32 + b) * 96 + off + tg];
    if (tid == 0) term += start[tg];
    else          term += trans[labels[(tid - 1) * 32 + b] * K + tg];
    if (tid == 127) term += end_[tg];
    red[tid] = term;
  }
  __syncthreads();
  if (tid == 0) {
    float num = 0.f;
    for (int i = 0; i < 128; ++i) num += red[i];
    float mx = -3e38f;
    for (int k = 0; k < K; ++k) mx = fmaxf(mx, alpha[p][k] + end_[k]);
    float ss = 0.f;
    for (int k = 0; k < K; ++k) ss += __expf(alpha[p][k] + end_[k] - mx);
    const float den = mx + __logf(ss);
    atomicAdd(outp, den - num);   // loss contribution = -(num - den)
  }
}

__global__ __launch_bounds__(256) void crf_kernel(
    const float* __restrict__ feat,
    const int* __restrict__ labp, const int* __restrict__ labm,
    const float* __restrict__ stp, const float* __restrict__ enp, const float* __restrict__ trp,
    const float* __restrict__ stm, const float* __restrict__ enm, const float* __restrict__ trm,
    float* __restrict__ outp)
{
  __shared__ float transT[64 * 65];
  __shared__ float alpha[2][64];
  __shared__ float red[128];
  const int task = blockIdx.x >> 5, b = blockIdx.x & 31;
  if (task == 0) crf_body<32>(feat, 0,  labp, b, stp, enp, trp, outp, transT, alpha, red);
  else           crf_body<64>(feat, 32, labm, b, stm, enm, trm, outp, transT, alpha, red);
}

// ---------------------------------------------------------------------------
// launch
// ---------------------------------------------------------------------------
extern "C" void kernel_launch(void* const* d_in, const int* in_sizes, int n_in,
                              void* d_out, int out_size, void* d_ws, size_t ws_size,
                              hipStream_t stream) {
  const float* src  = (const float*)d_in[0];
  const float* bert = (const float*)d_in[1];
  const int*   labp = (const int*)d_in[2];
  const int*   labm = (const int*)d_in[3];
  const float* w_ih = (const float*)d_in[4];
  const float* w_hh = (const float*)d_in[5];
  const float* b_ih = (const float*)d_in[6];
  const float* b_hh = (const float*)d_in[7];
  const float* hwp  = (const float*)d_in[8];
  const float* hbp  = (const float*)d_in[9];
  const float* hwm  = (const float*)d_in[10];
  const float* hbm  = (const float*)d_in[11];
  const float* stp  = (const float*)d_in[12];
  const float* enp  = (const float*)d_in[13];
  const float* trp  = (const float*)d_in[14];
  const float* stm  = (const float*)d_in[15];
  const float* enm  = (const float*)d_in[16];
  const float* trm  = (const float*)d_in[17];

  char* ws = (char*)d_ws;
  u16*   Wsrc     = (u16*)(ws + 0);          // 4096x256 bf16
  u16*   Wbert    = (u16*)(ws + 2097152);    // 4096x768 bf16
  u16*   Wih1     = (u16*)(ws + 8388608);    // 4096x1024 bf16
  u16*   Whh      = (u16*)(ws + 16777216);   // [2][2][2048][512] bf16
  u16*   SrcBf    = (u16*)(ws + 25165824);   // 4096x256 bf16
  u16*   BertBf   = (u16*)(ws + 27262976);   // 32x768 bf16
  u16*   Wheads   = (u16*)(ws + 27312128);   // 96x1024 bf16
  float* b0sum    = (float*)(ws + 27508736); // [4096]
  float* b1sum    = (float*)(ws + 27525120); // [4096]
  float* hb       = (float*)(ws + 27541504); // [96]
  float* bertpart = (float*)(ws + 27542272); // [32][4096]
  float* feat     = (float*)(ws + 28066560); // [4096][96]
  u16*   out0     = (u16*)(ws + 29639424);   // [128][32][1024] bf16
  u16*   out1     = (u16*)(ws + 38028032);   // [128][32][1024] bf16
  u16*   gates    = (u16*)(ws + 46416640);   // wave-ordered bf16 (32 MiB)
  u16*   gates1b  = (u16*)(ws + 79971072);   // second gate buffer (32 MiB)
  u32*   prog0    = (u32*)(ws + 113525504);  // [2][128] slab counters L0
  u32*   prog1    = (u32*)(ws + 113526528);  // [2][128] slab counters L1
  float* dout     = (float*)d_out;

  const bool bigws = (ws_size >= 113527552ULL);
  u16* g1 = bigws ? gates1b : gates;
  // !bigws: counters land in dead bertpart scratch (never read on that path)
  u32* p0 = bigws ? prog0 : (u32*)bertpart;
  u32* p1 = bigws ? prog1 : ((u32*)bertpart) + 256;

  // sentinel fill: bf16 0xFFFF = NaN, unreachable for valid h in (-1,1)
  hipMemsetAsync(out0, 0xFF, 8388608, stream);
  hipMemsetAsync(out1, 0xFF, 8388608, stream);
  if (bigws) hipMemsetAsync(prog0, 0, 2048, stream);

  hipLaunchKernelGGL(prep_kernel, dim3(2048), dim3(256), 0, stream,
      w_ih, w_hh, b_ih, b_hh, src, bert, hwp, hbp, hwm, hbm,
      Wsrc, Wbert, Wih1, Whh, SrcBf, BertBf, Wheads, b0sum, b1sum, hb, dout);

  // bert part: [32,768]@[4096,768]^T + (b_ih0+b_hh0) -> bertpart[32][4096]
  hipLaunchKernelGGL(gemm_nt, dim3(32, 1), dim3(256), 0, stream,
      BertBf, 768, Wbert, 768, bertpart, 4096, 32, 4096, 768,
      b0sum, (const float*)nullptr, 0, 0);

  // layer0 input proj: src@Wsrc^T + bertpart -> bf16 gates (wave-ordered)
  hipLaunchKernelGGL(gemm_nt, dim3(32, 32), dim3(256), 0, stream,
      SrcBf, 256, Wsrc, 256, (float*)gates, 0, 4096, 4096, 256,
      (const float*)nullptr, bertpart, 4096, 1);

  {
    int ph0 = 0, ph1 = 1;
    const u16* gin0 = gates; const u16* gin1 = g1;
    u16* gout = g1; u16* o0 = out0; u16* o1 = out1;
    const u16* whh0 = Whh; const u16* whh1 = Whh + 2L * 2048 * 512;
    const u16* wih1 = Wih1; const float* b1 = b1sum;
    const u16* whd = Wheads; const float* hbp2 = hb; float* ft = feat;

    // COOP A: lstm layer0 + gates1 producers (counter-gated)
    const dim3 gridA(bigws ? 384 : 128);
    void* args0[] = {&ph0, &gin0, &gout, &o0, &whh0, &wih1, &b1, &whd, &hbp2,
                     &ft, &p0};
    if (hipLaunchCooperativeKernel(reinterpret_cast<void*>(&fused_lstm),
                                   gridA, dim3(256), args0, 0, stream)
        != hipSuccess) {
      hipLaunchKernelGGL(fused_lstm, gridA, dim3(256), 0, stream,
          ph0, gin0, gout, o0, whh0, wih1, b1, whd, hbp2, ft, p0);
    }

    if (!bigws) {
      // fallback: standalone gates1 GEMM into the single gate buffer
      hipLaunchKernelGGL(gemm_nt, dim3(32, 32), dim3(256), 0, stream,
          out0, 1024, Wih1, 1024, (float*)gates, 0, 4096, 4096, 1024,
          b1sum, (const float*)nullptr, 0, 1);
    }

    // COOP B: lstm layer1 + fused heads GEMM (counter-gated)
    const dim3 gridB(bigws ? 160 : 128);
    void* args1[] = {&ph1, &gin1, &gout, &o1, &whh1, &wih1, &b1, &whd, &hbp2,
                     &ft, &p1};
    if (hipLaunchCooperativeKernel(reinterpret_cast<void*>(&fused_lstm),
                                   gridB, dim3(256), args1, 0, stream)
        != hipSuccess) {
      hipLaunchKernelGGL(fused_lstm, gridB, dim3(256), 0, stream,
          ph1, gin1, gout, o1, whh1, wih1, b1, whd, hbp2, ft, p1);
    }

    if (!bigws) {
      // fallback: standalone heads GEMM
      hipLaunchKernelGGL(gemm_nt, dim3(1, 32), dim3(256), 0, stream,
          out1, 1024, Wheads, 1024, feat, 96, 4096, 96, 1024,
          hb, (const float*)nullptr, 0, 0);
    }
  }

  hipLaunchKernelGGL(crf_kernel, dim3(64), dim3(256), 0, stream,
      feat, labp, labm, stp, enp, trp, stm, enm, trm, dout);
}

// Round 5
// 1194.204 us; speedup vs baseline: 1.3702x; 1.3702x over previous
//
#include <hip/hip_runtime.h>

// ---------------------------------------------------------------------------
// BiLSTM-CRF forward loss on MI355X (gfx950).
// R12: fused producers with contention-free signaling.
//   R10 failure: consumer bulk spin sweeps (2048 atomic loads/round) saturate
//     the MALL -> lstm stretched to 450+.
//   R11 failure: per-step same-address atomicAdd (256 RMWs/step) serialized
//     at the coherence point; vmcnt drain before each step barrier makes
//     every lstm block pay the RMW queue -> both phases ~760.
//   R12: per-BLOCK progress flag (plain relaxed store, unique address) +
//     wave-ballot poll gate in consumers (64 lanes, 1 flag each, s_sleep
//     backoff). One-shot A sweep + sentinel backstop kept for correctness.
//     Phase0 grid 256 (128 lstm + 128 producers x 8 tiles, middle-out).
// Chain: memsets -> prep -> bert GEMM -> gates0 GEMM
//   -> COOP A (256): lstm L0 + gates1 producers -> COOP B (160): lstm L1 +
//      heads -> CRF.  !bigws fallback = fully serial (R7 path).
// ---------------------------------------------------------------------------

typedef unsigned short u16;
typedef unsigned int u32;
typedef unsigned long long u64;
typedef __attribute__((ext_vector_type(8))) __bf16 bf16x8;
typedef __attribute__((ext_vector_type(4))) float floatx4;

static __device__ __forceinline__ u16 f2bf(float f) {
  u32 u = __float_as_uint(f);
  u += 0x7fffu + ((u >> 16) & 1u);   // round-to-nearest-even
  return (u16)(u >> 16);
}
static __device__ __forceinline__ float bf2f(u32 bits) {
  return __uint_as_float(bits << 16);
}
static __device__ __forceinline__ float sigf(float x) {
  return 1.0f / (1.0f + __expf(-x));
}
static __device__ __forceinline__ float tanh_(float x) {
  return 1.0f - 2.0f / (1.0f + __expf(2.0f * x));
}
static __device__ __forceinline__ floatx4 mfma16(bf16x8 a, bf16x8 b, floatx4 c) {
  return __builtin_amdgcn_mfma_f32_16x16x32_bf16(a, b, c, 0, 0, 0);
}
static __device__ __forceinline__ u64 aload64(const u64* p) {
  return __hip_atomic_load((u64*)p, __ATOMIC_RELAXED, __HIP_MEMORY_SCOPE_AGENT);
}
static __device__ __forceinline__ void astore64(u64* p, u64 v) {
  __hip_atomic_store(p, v, __ATOMIC_RELAXED, __HIP_MEMORY_SCOPE_AGENT);
}
static __device__ __forceinline__ u32 aload32(const u32* p) {
  return __hip_atomic_load((u32*)p, __ATOMIC_RELAXED, __HIP_MEMORY_SCOPE_AGENT);
}
static __device__ __forceinline__ void astore32(u32* p, u32 v) {
  __hip_atomic_store(p, v, __ATOMIC_RELAXED, __HIP_MEMORY_SCOPE_AGENT);
}

// ---------------------------------------------------------------------------
// prep: fp32->bf16 conversions + bias sums + zero d_out
// ---------------------------------------------------------------------------
__global__ __launch_bounds__(256) void prep_kernel(
    const float* __restrict__ w_ih, const float* __restrict__ w_hh,
    const float* __restrict__ b_ih, const float* __restrict__ b_hh,
    const float* __restrict__ src,  const float* __restrict__ bert,
    const float* __restrict__ hwp,  const float* __restrict__ hbp,
    const float* __restrict__ hwm,  const float* __restrict__ hbm,
    u16* __restrict__ Wsrc, u16* __restrict__ Wbert, u16* __restrict__ Wih1,
    u16* __restrict__ Whh,  u16* __restrict__ SrcBf, u16* __restrict__ BertBf,
    u16* __restrict__ Wheads, float* __restrict__ b0sum, float* __restrict__ b1sum,
    float* __restrict__ hb, float* __restrict__ dout)
{
  const int NA = 4194304;  // w_ih layer0 -> Wsrc (cols 0:256) + Wbert (256:1024)
  const int NB = 4194304;  // w_ih layer1
  const int NC = 4194304;  // w_hh (both layers)
  const int ND = 1048576;  // src
  const int NE = 24576;    // bert
  const int NF = 98304;    // head weights
  const int NG = 8192;     // bias sums
  const int NH = 96;       // head bias
  const int TOTAL = NA + NB + NC + ND + NE + NF + NG + NH + 1;
  for (int i = blockIdx.x * 256 + threadIdx.x; i < TOTAL; i += gridDim.x * 256) {
    int x = i;
    if (x < NA) {
      int c = x & 1023, r = x >> 10;          // r = dir*2048 + row
      float v = w_ih[x];
      if (c < 256) Wsrc[r * 256 + c] = f2bf(v);
      else         Wbert[r * 768 + (c - 256)] = f2bf(v);
      continue;
    }
    x -= NA;
    if (x < NB) { Wih1[x] = f2bf(w_ih[NA + x]); continue; }
    x -= NB;
    if (x < NC) { Whh[x] = f2bf(w_hh[x]); continue; }
    x -= NC;
    if (x < ND) { SrcBf[x] = f2bf(src[x]); continue; }
    x -= ND;
    if (x < NE) { BertBf[x] = f2bf(bert[x]); continue; }
    x -= NE;
    if (x < NF) {
      Wheads[x] = f2bf(x < 32768 ? hwp[x] : hwm[x - 32768]);
      continue;
    }
    x -= NF;
    if (x < NG) {
      float v = b_ih[x] + b_hh[x];
      if (x < 4096) b0sum[x] = v; else b1sum[x - 4096] = v;
      continue;
    }
    x -= NG;
    if (x < NH) { hb[x] = (x < 32) ? hbp[x] : hbm[x - 32]; continue; }
    dout[0] = 0.f;
  }
}

// ---------------------------------------------------------------------------
// standalone bf16 NT GEMM (R7-exact): acc[m][n] = sum_k A[m][k]*B[n][k]
// (+bias[n]) (+aux[m%32][n]). 128x128 tile, BK=64, XOR-swizzled LDS.
// mode 0: C fp32. mode 1: bf16 gates, wave-ordered u64 layout.
// ---------------------------------------------------------------------------
__global__ __launch_bounds__(256) void gemm_nt(
    const u16* __restrict__ A, int lda,
    const u16* __restrict__ B, int ldb,
    float* __restrict__ C, int ldc,
    int M, int N, int K,
    const float* __restrict__ bias_n,
    const float* __restrict__ auxBN, int auxld,
    int mode)
{
  __shared__ __align__(16) u16 As[128 * 64];
  __shared__ __align__(16) u16 Bs[128 * 64];
  const int m0 = blockIdx.y * 128, n0 = blockIdx.x * 128;
  const int tid = threadIdx.x;
  const int wv = tid >> 6, ln = tid & 63;
  const int wm = wv & 1, wn = wv >> 1;
  const int q = ln >> 4, l15 = ln & 15;
  floatx4 acc[4][4];
#pragma unroll
  for (int a = 0; a < 4; ++a)
#pragma unroll
    for (int b2 = 0; b2 < 4; ++b2) acc[a][b2] = (floatx4){0.f, 0.f, 0.f, 0.f};

  for (int kk = 0; kk < K; kk += 64) {
    __syncthreads();
#pragma unroll
    for (int j = 0; j < 4; ++j) {
      const int idx = j * 256 + tid;   // 1024 16B chunks per operand tile
      const int r = idx >> 3, cc = idx & 7;
      const int slot = cc ^ (r & 7);
      const int ra = min(m0 + r, M - 1);
      *(int4*)&As[r * 64 + slot * 8] = *(const int4*)&A[(long)ra * lda + kk + cc * 8];
      const int rb = min(n0 + r, N - 1);
      *(int4*)&Bs[r * 64 + slot * 8] = *(const int4*)&B[(long)rb * ldb + kk + cc * 8];
    }
    __syncthreads();
#pragma unroll
    for (int ks = 0; ks < 2; ++ks) {
      bf16x8 af[4], bf[4];
#pragma unroll
      for (int im = 0; im < 4; ++im) {
        const int r = wm * 64 + im * 16 + l15;
        const int slot = (ks * 4 + q) ^ (r & 7);
        af[im] = *(const bf16x8*)&As[r * 64 + slot * 8];
      }
#pragma unroll
      for (int jn = 0; jn < 4; ++jn) {
        const int r = wn * 64 + jn * 16 + l15;
        const int slot = (ks * 4 + q) ^ (r & 7);
        bf[jn] = *(const bf16x8*)&Bs[r * 64 + slot * 8];
      }
#pragma unroll
      for (int im = 0; im < 4; ++im)
#pragma unroll
        for (int jn = 0; jn < 4; ++jn)
          acc[im][jn] = mfma16(af[im], bf[jn], acc[im][jn]);
    }
  }
  // epilogue: C/D layout col=lane&15, row=(lane>>4)*4+reg
  if (mode == 0) {
#pragma unroll
    for (int im = 0; im < 4; ++im)
#pragma unroll
      for (int jn = 0; jn < 4; ++jn) {
        const int n = n0 + wn * 64 + jn * 16 + l15;
        if (n < N) {
          const float badd = bias_n ? bias_n[n] : 0.f;
#pragma unroll
          for (int rg = 0; rg < 4; ++rg) {
            const int m = m0 + wm * 64 + im * 16 + q * 4 + rg;
            if (m < M) {
              float v = acc[im][jn][rg] + badd;
              if (auxBN) v += auxBN[(long)(m & 31) * auxld + n];
              C[(long)m * ldc + n] = v;
            }
          }
        }
      }
  } else {
    u64* G = (u64*)C;
#pragma unroll
    for (int im = 0; im < 4; ++im)
#pragma unroll
      for (int jn = 0; jn < 4; ++jn) {
        const int n = n0 + wn * 64 + jn * 16 + l15;
        const int dirsel = n >> 11, nn = n & 2047;
        const int gt = nn >> 9, u = nn & 511;
        const int ub = u >> 4, low = u & 15;
        const int wvl = low >> 2, jl = low & 3;
        const int l15l = gt * 4 + jl;
        const int m = m0 + wm * 64 + im * 16 + q * 4;   // rg=0 row
        const int s = m >> 5, b0 = m & 31;
        const int mh = b0 >> 4, qq = (b0 >> 2) & 3;
        const float badd = bias_n ? bias_n[n] : 0.f;
        u64 pk = 0;
#pragma unroll
        for (int rg = 0; rg < 4; ++rg) {
          float v = acc[im][jn][rg] + badd;
          if (auxBN) v += auxBN[(long)(b0 + rg) * auxld + n];
          pk |= (u64)f2bf(v) << (16 * rg);
        }
        G[(((((long)dirsel * 128 + s) * 2 + mh) * 32 + ub) * 4 + wvl) * 64
          + l15l * 4 + qq] = pk;
      }
  }
}

// ---------------------------------------------------------------------------
// fused GEMM tile: one 128x128 output tile; spinA=1 stages A rows produced
// concurrently by lstm blocks. Gate: wave-0 ballot over per-block progress
// flags (flags[bid]=last completed step t). Then one-shot atomic u64 sweep +
// sentinel-retry backstop (relaxed-ordering safety net).
// mode 0: fp32 C. mode 1: wave-ordered bf16 gate u64, plain store.
// ---------------------------------------------------------------------------
static __device__ void gemm_tile(
    const u16* __restrict__ A, int lda,
    const u16* __restrict__ B, int ldb,
    float* __restrict__ C, int ldc,
    int m0, int n0, int M, int N, int K,
    const float* __restrict__ bias_n,
    int mode, int spinA, const u32* __restrict__ flags, u16* smem)
{
  u16* As = smem;             // [128*64]
  u16* Bs = smem + 128 * 64;  // [128*64]
  const int tid = threadIdx.x;
  const int wv = tid >> 6, ln = tid & 63;
  const int wm = wv & 1, wn = wv >> 1;
  const int q = ln >> 4, l15 = ln & 15;
  floatx4 acc[4][4];
#pragma unroll
  for (int a = 0; a < 4; ++a)
#pragma unroll
    for (int b2 = 0; b2 < 4; ++b2) acc[a][b2] = (floatx4){0.f, 0.f, 0.f, 0.f};

  for (int kk = 0; kk < K; kk += 64) {
    __syncthreads();
    if (spinA && (kk == 0 || kk == 512)) {
      // Gate this K-half on the producing direction's progress. Lane ln
      // watches lstm block (dsel*64+ln); all 64 must pass req.
      if (wv == 0) {
        const int dsel = kk >> 9;
        const int s0 = m0 >> 5;
        const int req = dsel ? (127 - s0) : (s0 + 3);
        for (;;) {
          const int f = (int)aload32(&flags[dsel * 64 + ln]);
          if (__all(f >= req)) break;
          __builtin_amdgcn_s_sleep(32);
        }
      }
      __syncthreads();
    }
    if (spinA) {
      // A rows are lstm h outputs: one coalesced atomic sweep (flags say the
      // data is ready); sentinel retry as relaxed-ordering backstop.
      u64 va[8];
#pragma unroll
      for (int j = 0; j < 8; ++j) {
        const int idx = j * 256 + tid;
        const int r = idx >> 4, cc = idx & 15;
        va[j] = aload64((const u64*)&A[(long)(m0 + r) * lda + kk + cc * 4]);
      }
      while (true) {
        bool bad = false;
#pragma unroll
        for (int j = 0; j < 8; ++j) bad |= ((va[j] & 0xffffULL) == 0xffffULL);
        if (!bad) break;
        __builtin_amdgcn_s_sleep(16);
#pragma unroll
        for (int j = 0; j < 8; ++j)
          if ((va[j] & 0xffffULL) == 0xffffULL) {
            const int idx = j * 256 + tid;
            const int r = idx >> 4, cc = idx & 15;
            va[j] = aload64((const u64*)&A[(long)(m0 + r) * lda + kk + cc * 4]);
          }
      }
#pragma unroll
      for (int j = 0; j < 8; ++j) {
        const int idx = j * 256 + tid;
        const int r = idx >> 4, cc = idx & 15;
        const int ch = cc >> 1, hf = cc & 1;
        *(u64*)&As[r * 64 + ((ch ^ (r & 7)) << 3) + (hf << 2)] = va[j];
      }
    } else {
#pragma unroll
      for (int j = 0; j < 4; ++j) {
        const int idx = j * 256 + tid;
        const int r = idx >> 3, cc = idx & 7;
        const int slot = cc ^ (r & 7);
        const int ra = min(m0 + r, M - 1);
        *(int4*)&As[r * 64 + slot * 8] = *(const int4*)&A[(long)ra * lda + kk + cc * 8];
      }
    }
#pragma unroll
    for (int j = 0; j < 4; ++j) {
      const int idx = j * 256 + tid;
      const int r = idx >> 3, cc = idx & 7;
      const int slot = cc ^ (r & 7);
      const int rb = min(n0 + r, N - 1);
      *(int4*)&Bs[r * 64 + slot * 8] = *(const int4*)&B[(long)rb * ldb + kk + cc * 8];
    }
    __syncthreads();
#pragma unroll
    for (int ks = 0; ks < 2; ++ks) {
      bf16x8 af[4], bf[4];
#pragma unroll
      for (int im = 0; im < 4; ++im) {
        const int r = wm * 64 + im * 16 + l15;
        const int slot = (ks * 4 + q) ^ (r & 7);
        af[im] = *(const bf16x8*)&As[r * 64 + slot * 8];
      }
#pragma unroll
      for (int jn = 0; jn < 4; ++jn) {
        const int r = wn * 64 + jn * 16 + l15;
        const int slot = (ks * 4 + q) ^ (r & 7);
        bf[jn] = *(const bf16x8*)&Bs[r * 64 + slot * 8];
      }
#pragma unroll
      for (int im = 0; im < 4; ++im)
#pragma unroll
        for (int jn = 0; jn < 4; ++jn)
          acc[im][jn] = mfma16(af[im], bf[jn], acc[im][jn]);
    }
  }
  // epilogue: C/D layout col=lane&15, row=(lane>>4)*4+reg
  if (mode == 0) {
#pragma unroll
    for (int im = 0; im < 4; ++im)
#pragma unroll
      for (int jn = 0; jn < 4; ++jn) {
        const int n = n0 + wn * 64 + jn * 16 + l15;
        if (n < N) {
          const float badd = bias_n ? bias_n[n] : 0.f;
#pragma unroll
          for (int rg = 0; rg < 4; ++rg) {
            const int m = m0 + wm * 64 + im * 16 + q * 4 + rg;
            if (m < M) C[(long)m * ldc + n] = acc[im][jn][rg] + badd;
          }
        }
      }
  } else {
    u64* G = (u64*)C;
#pragma unroll
    for (int im = 0; im < 4; ++im)
#pragma unroll
      for (int jn = 0; jn < 4; ++jn) {
        const int n = n0 + wn * 64 + jn * 16 + l15;
        const int dirsel = n >> 11, nn = n & 2047;
        const int gt = nn >> 9, u = nn & 511;
        const int ub2 = u >> 4, low = u & 15;
        const int wvl = low >> 2, jl = low & 3;
        const int l15l = gt * 4 + jl;
        const int m = m0 + wm * 64 + im * 16 + q * 4;   // rg=0 row
        const int s = m >> 5, b0 = m & 31;
        const int mh2 = b0 >> 4, qq = (b0 >> 2) & 3;
        const float badd = bias_n ? bias_n[n] : 0.f;
        u64 pk = 0;
#pragma unroll
        for (int rg = 0; rg < 4; ++rg)
          pk |= (u64)f2bf(acc[im][jn][rg] + badd) << (16 * rg);
        G[(((((long)dirsel * 128 + s) * 2 + mh2) * 32 + ub2) * 4 + wvl) * 64
          + l15l * 4 + qq] = pk;
      }
  }
}

// ---------------------------------------------------------------------------
// LSTM recurrence body (R7 protocol + per-block progress flag: plain relaxed
// store of the completed step index; unique address per block -> no RMW).
// block = (dir, batch-half of 16, 16 units). Gates read with plain loads.
// ---------------------------------------------------------------------------
static __device__ void lstm_body(const u16* __restrict__ gates,
                                 u16* __restrict__ out,
                                 const u16* __restrict__ whh,
                                 u32* __restrict__ flags,
                                 u16* h_lds, float* gscf)
{
  const int bid = blockIdx.x;
  const int dir = bid >> 6;
  const int mh = (bid >> 5) & 1;
  const int ub = bid & 31;
  const int u0 = ub * 16;
  const int tid = threadIdx.x;
  const int wv = tid >> 6;
  const int ln = tid & 63;
  const int q = ln >> 4, l15 = ln & 15;

  // gate row for this lane's B-frag column n=l15: (n>>2)=gate type, (n&3)=unit
  const int gate_r = (l15 >> 2) * 512 + u0 + wv * 4 + (l15 & 3);

  bf16x8 bfrag[16];
  {
    const u16* wp = whh + ((long)dir * 2048 + gate_r) * 512 + q * 8;
#pragma unroll
    for (int ks = 0; ks < 16; ++ks)
      bfrag[ks] = *(const bf16x8*)(wp + ks * 32);
  }

  float c = 0.f;                       // cell state for (b_glob, j_lane)
  const int b_glob = mh * 16 + l15;    // batch (update phase)

  // wave-ordered gate pointer: stride per s = 2*32*4*64 = 16384 u64
  const u64* gbase = (const u64*)gates
      + ((((long)dir * 128 * 2 + mh) * 32 + ub) * 4 + wv) * 64 + l15 * 4 + q;

  u64 gcur = gbase[(long)(dir ? 127 : 0) * 16384];
  u64 gnext = 0;

  for (int t = 0; t < 128; ++t) {
    const int s = dir ? (127 - t) : t;
    // gate prefetch for t+1: coalesced 512 B per wave, issued before staging
    if (t < 127) {
      const int sn = dir ? (126 - t) : (t + 1);
      gnext = gbase[(long)sn * 16384];
    }
    floatx4 acc = (floatx4){0.f, 0.f, 0.f, 0.f};
    if (t > 0) {
      // stage h(t-1): 16 rows x 512 cols bf16. Coalesced device-scope u64
      // loads; each u64 = one producer wave's atomic store -> check low u16.
      const int sp = dir ? (s + 1) : (s - 1);
      const u64* ubp = (const u64*)(out + (((long)sp * 32 + mh * 16) * 1024 + (long)dir * 512));
      u64 v8[8];
#pragma unroll
      for (int j = 0; j < 8; ++j) {
        const int idx = j * 256 + tid;           // 2048 u64 chunks
        const int r = idx >> 7, c4 = idx & 127;  // row, u64-within-row
        v8[j] = aload64(ubp + (long)r * 256 + c4);
      }
      while (true) {
        bool bad = false;
#pragma unroll
        for (int j = 0; j < 8; ++j) bad |= ((v8[j] & 0xffffULL) == 0xffffULL);
        if (!bad) break;
#pragma unroll
        for (int j = 0; j < 8; ++j) {
          if ((v8[j] & 0xffffULL) == 0xffffULL) {
            const int idx = j * 256 + tid;
            const int r = idx >> 7, c4 = idx & 127;
            v8[j] = aload64(ubp + (long)r * 256 + c4);
          }
        }
      }
#pragma unroll
      for (int j = 0; j < 8; ++j) {
        const int idx = j * 256 + tid;
        const int r = idx >> 7, c4 = idx & 127;
        const int cc8 = c4 >> 1, hf = c4 & 1;
        *(u64*)&h_lds[r * 512 + ((cc8 ^ (r & 7)) << 3) + (hf << 2)] = v8[j];
      }
      __syncthreads();   // the ONLY barrier per step
      floatx4 acc1 = (floatx4){0.f, 0.f, 0.f, 0.f};
#pragma unroll
      for (int ks = 0; ks < 16; ks += 2) {   // 2 chains to halve dep latency
        const int slot0 = (ks * 4 + q) ^ (l15 & 7);
        bf16x8 a0 = *(const bf16x8*)&h_lds[l15 * 512 + slot0 * 8];
        acc = mfma16(a0, bfrag[ks], acc);
        const int slot1 = ((ks + 1) * 4 + q) ^ (l15 & 7);
        bf16x8 a1 = *(const bf16x8*)&h_lds[l15 * 512 + slot1 * 8];
        acc1 = mfma16(a1, bfrag[ks + 1], acc1);
      }
      acc += acc1;
    }
    // C-frag (row=batch=q*4+rg, col=n=l15) -> wave-local LDS transpose
#pragma unroll
    for (int rg = 0; rg < 4; ++rg)
      gscf[(wv * 16 + q * 4 + rg) * 17 + l15] =
          acc[rg] + bf2f((u32)((gcur >> (16 * rg)) & 0xffffu));
    // gscf wave slice touched only by wave wv: wave-synchronous, no barrier
    const float gi = gscf[(wv * 16 + l15) * 17 + q];
    const float gf = gscf[(wv * 16 + l15) * 17 + 4 + q];
    const float gg = gscf[(wv * 16 + l15) * 17 + 8 + q];
    const float go = gscf[(wv * 16 + l15) * 17 + 12 + q];
    const float iv = sigf(gi), fv = sigf(gf), gv = tanh_(gg), ov = sigf(go);
    c = fv * c + iv * gv;
    const float h = ov * tanh_(c);
    // pack 4 units (quads q=0..3, lanes 16 apart) -> one u64 store by q==0
    const u32 hv = (u32)f2bf(h);
    const u32 p1 = (u32)__shfl_xor((int)hv, 16);
    const u32 lo32 = hv | (p1 << 16);
    const u64 w64 = (u64)lo32 |
                    ((u64)(u32)__shfl_xor((int)lo32, 32) << 32);
    if (q == 0)
      astore64((u64*)&out[((long)s * 32 + b_glob) * 1024 + dir * 512 + u0 + wv * 4], w64);
    // publish progress: one plain relaxed store to a block-unique word.
    // Hint only (consumers keep the sentinel backstop) -> no fencing needed.
    if (tid == 0) astore32(&flags[bid], (u32)t);
    gcur = gnext;
  }
}

// ---------------------------------------------------------------------------
// fused cooperative kernel. 32 KiB LDS arena.
// phase 0 (grid 256): bid<128 lstm L0 -> flags; bid>=128: 8 gates1 tiles
//   middle-out into gatesOut, flag-gated A=out0.
// phase 1 (grid 160): bid<128 lstm L1 -> flags; bid 128..159 heads tiles.
// ---------------------------------------------------------------------------
__global__ __launch_bounds__(256, 1) void fused_lstm(
    int phase,
    const u16* __restrict__ gatesIn,
    u16* __restrict__ gatesOut,
    u16* __restrict__ outw,
    const u16* __restrict__ whh,
    const u16* __restrict__ Wih1, const float* __restrict__ b1sum,
    const u16* __restrict__ Wheads, const float* __restrict__ hb,
    float* __restrict__ feat,
    u32* __restrict__ flags)
{
  __shared__ __align__(16) u16 smem[16384];   // 32768 B (gemm uses all;
  const int bid = blockIdx.x;                 //  lstm carves 20736 B)
  if (bid < 128) {
    u16* h_lds = smem;                       // 16384 B
    float* gscf = (float*)(smem + 8192);     // 4352 B at byte 16384
    lstm_body(gatesIn, outw, whh, flags, h_lds, gscf);
  } else if (phase == 0) {
    const int g = bid - 128;                 // 0..127
    // gates1: out0 @ Wih1^T + b1sum -> gatesOut, middle-out M order
    for (int ord = 0; ord < 8; ++ord) {
      const int t = ord * 128 + g;
      const int k = t >> 5, cn = t & 31;
      const int rm = (k & 1) ? (16 + (k >> 1)) : (15 - (k >> 1));
      gemm_tile(outw, 1024, Wih1, 1024, (float*)gatesOut, 0,
                rm * 128, cn * 128, 4096, 4096, 1024,
                b1sum, 1, 1, flags, smem);
    }
  } else if (bid < 160) {
    const int g = bid - 128;                 // 0..31
    const int rm = (g & 1) ? (16 + (g >> 1)) : (15 - (g >> 1));
    gemm_tile(outw, 1024, Wheads, 1024, feat, 96,
              rm * 128, 0, 4096, 96, 1024,
              hb, 0, 1, flags, smem);
  }
}

// ---------------------------------------------------------------------------
// CRF: one block per (task, batch). Double-buffered alpha: 1 barrier/step.
// ---------------------------------------------------------------------------
template <int K>
static __device__ void crf_body(const float* __restrict__ feat, int off,
                                const int* __restrict__ labels, int b,
                                const float* __restrict__ start,
                                const float* __restrict__ end_,
                                const float* __restrict__ trans,
                                float* __restrict__ outp,
                                float* transT, float (*alpha)[64],
                                float* red)
{
  const int tid = threadIdx.x;
  for (int i = tid; i < K * K; i += 256) {
    int kk = i / K, kp2 = i % K;
    transT[kp2 * 65 + kk] = trans[i];
  }
  if (tid < K) alpha[0][tid] = start[tid] + feat[b * 96 + off + tid];
  __syncthreads();
  constexpr int Kq = K / 4;
  const int kp = tid >> 2, k4 = tid & 3;
  const bool act = kp < K;
  int p = 0;
  for (int s = 1; s < 128; ++s) {
    float x[Kq];
    float mx = -3e38f;
    if (act) {
      const float* tr = &transT[kp * 65 + k4 * Kq];
      const float* al = &alpha[p][k4 * Kq];
#pragma unroll
      for (int i2 = 0; i2 < Kq; ++i2) { x[i2] = al[i2] + tr[i2]; mx = fmaxf(mx, x[i2]); }
    }
    mx = fmaxf(mx, __shfl_xor(mx, 1));
    mx = fmaxf(mx, __shfl_xor(mx, 2));
    float ss = 0.f;
    if (act) {
#pragma unroll
      for (int i2 = 0; i2 < Kq; ++i2) ss += __expf(x[i2] - mx);
    }
    ss += __shfl_xor(ss, 1);
    ss += __shfl_xor(ss, 2);
    if (act && k4 == 0)
      alpha[p ^ 1][kp] = mx + __logf(ss) + feat[(s * 32 + b) * 96 + off + kp];
    __syncthreads();
    p ^= 1;
  }
  // numerator terms (one per time step)
  if (tid < 128) {
    const int tg = labels[tid * 32 + b];
    float term = feat[(tid * 32 + b) * 96 + off + tg];
    if (tid == 0) term += start[tg];
    else          term += trans[labels[(tid - 1) * 32 + b] * K + tg];
    if (tid == 127) term += end_[tg];
    red[tid] = term;
  }
  __syncthreads();
  if (tid == 0) {
    float num = 0.f;
    for (int i = 0; i < 128; ++i) num += red[i];
    float mx = -3e38f;
    for (int k = 0; k < K; ++k) mx = fmaxf(mx, alpha[p][k] + end_[k]);
    float ss = 0.f;
    for (int k = 0; k < K; ++k) ss += __expf(alpha[p][k] + end_[k] - mx);
    const float den = mx + __logf(ss);
    atomicAdd(outp, den - num);   // loss contribution = -(num - den)
  }
}

__global__ __launch_bounds__(256) void crf_kernel(
    const float* __restrict__ feat,
    const int* __restrict__ labp, const int* __restrict__ labm,
    const float* __restrict__ stp, const float* __restrict__ enp, const float* __restrict__ trp,
    const float* __restrict__ stm, const float* __restrict__ enm, const float* __restrict__ trm,
    float* __restrict__ outp)
{
  __shared__ float transT[64 * 65];
  __shared__ float alpha[2][64];
  __shared__ float red[128];
  const int task = blockIdx.x >> 5, b = blockIdx.x & 31;
  if (task == 0) crf_body<32>(feat, 0,  labp, b, stp, enp, trp, outp, transT, alpha, red);
  else           crf_body<64>(feat, 32, labm, b, stm, enm, trm, outp, transT, alpha, red);
}

// ---------------------------------------------------------------------------
// launch
// ---------------------------------------------------------------------------
extern "C" void kernel_launch(void* const* d_in, const int* in_sizes, int n_in,
                              void* d_out, int out_size, void* d_ws, size_t ws_size,
                              hipStream_t stream) {
  const float* src  = (const float*)d_in[0];
  const float* bert = (const float*)d_in[1];
  const int*   labp = (const int*)d_in[2];
  const int*   labm = (const int*)d_in[3];
  const float* w_ih = (const float*)d_in[4];
  const float* w_hh = (const float*)d_in[5];
  const float* b_ih = (const float*)d_in[6];
  const float* b_hh = (const float*)d_in[7];
  const float* hwp  = (const float*)d_in[8];
  const float* hbp  = (const float*)d_in[9];
  const float* hwm  = (const float*)d_in[10];
  const float* hbm  = (const float*)d_in[11];
  const float* stp  = (const float*)d_in[12];
  const float* enp  = (const float*)d_in[13];
  const float* trp  = (const float*)d_in[14];
  const float* stm  = (const float*)d_in[15];
  const float* enm  = (const float*)d_in[16];
  const float* trm  = (const float*)d_in[17];

  char* ws = (char*)d_ws;
  u16*   Wsrc     = (u16*)(ws + 0);          // 4096x256 bf16
  u16*   Wbert    = (u16*)(ws + 2097152);    // 4096x768 bf16
  u16*   Wih1     = (u16*)(ws + 8388608);    // 4096x1024 bf16
  u16*   Whh      = (u16*)(ws + 16777216);   // [2][2][2048][512] bf16
  u16*   SrcBf    = (u16*)(ws + 25165824);   // 4096x256 bf16
  u16*   BertBf   = (u16*)(ws + 27262976);   // 32x768 bf16
  u16*   Wheads   = (u16*)(ws + 27312128);   // 96x1024 bf16
  float* b0sum    = (float*)(ws + 27508736); // [4096]
  float* b1sum    = (float*)(ws + 27525120); // [4096]
  float* hb       = (float*)(ws + 27541504); // [96]
  float* bertpart = (float*)(ws + 27542272); // [32][4096]
  float* feat     = (float*)(ws + 28066560); // [4096][96]
  u16*   out0     = (u16*)(ws + 29639424);   // [128][32][1024] bf16
  u16*   out1     = (u16*)(ws + 38028032);   // [128][32][1024] bf16
  u16*   gates    = (u16*)(ws + 46416640);   // wave-ordered bf16 (32 MiB)
  u16*   gates1b  = (u16*)(ws + 79971072);   // second gate buffer (32 MiB)
  u32*   flags0   = (u32*)(ws + 113525504);  // [128] progress flags L0
  u32*   flags1   = (u32*)(ws + 113526016);  // [128] progress flags L1
  float* dout     = (float*)d_out;

  const bool bigws = (ws_size >= 113526528ULL);
  u16* g1 = bigws ? gates1b : gates;
  // !bigws: flags land in dead bertpart scratch (no consumer reads them)
  u32* f0 = bigws ? flags0 : (u32*)bertpart;
  u32* f1 = bigws ? flags1 : ((u32*)bertpart) + 128;

  // sentinel fill: bf16 0xFFFF = NaN, unreachable for valid h in (-1,1);
  // flags init -1 (u32 0xFFFFFFFF) = "no step completed"
  hipMemsetAsync(out0, 0xFF, 8388608, stream);
  hipMemsetAsync(out1, 0xFF, 8388608, stream);
  if (bigws) hipMemsetAsync(flags0, 0xFF, 1024, stream);

  hipLaunchKernelGGL(prep_kernel, dim3(2048), dim3(256), 0, stream,
      w_ih, w_hh, b_ih, b_hh, src, bert, hwp, hbp, hwm, hbm,
      Wsrc, Wbert, Wih1, Whh, SrcBf, BertBf, Wheads, b0sum, b1sum, hb, dout);

  // bert part: [32,768]@[4096,768]^T + (b_ih0+b_hh0) -> bertpart[32][4096]
  hipLaunchKernelGGL(gemm_nt, dim3(32, 1), dim3(256), 0, stream,
      BertBf, 768, Wbert, 768, bertpart, 4096, 32, 4096, 768,
      b0sum, (const float*)nullptr, 0, 0);

  // layer0 input proj: src@Wsrc^T + bertpart -> bf16 gates (wave-ordered)
  hipLaunchKernelGGL(gemm_nt, dim3(32, 32), dim3(256), 0, stream,
      SrcBf, 256, Wsrc, 256, (float*)gates, 0, 4096, 4096, 256,
      (const float*)nullptr, bertpart, 4096, 1);

  {
    int ph0 = 0, ph1 = 1;
    const u16* gin0 = gates; const u16* gin1 = g1;
    u16* gout = g1; u16* o0 = out0; u16* o1 = out1;
    const u16* whh0 = Whh; const u16* whh1 = Whh + 2L * 2048 * 512;
    const u16* wih1 = Wih1; const float* b1 = b1sum;
    const u16* whd = Wheads; const float* hbp2 = hb; float* ft = feat;

    // COOP A: lstm layer0 + gates1 producers (flag-gated)
    const dim3 gridA(bigws ? 256 : 128);
    void* args0[] = {&ph0, &gin0, &gout, &o0, &whh0, &wih1, &b1, &whd, &hbp2,
                     &ft, &f0};
    if (hipLaunchCooperativeKernel(reinterpret_cast<void*>(&fused_lstm),
                                   gridA, dim3(256), args0, 0, stream)
        != hipSuccess) {
      hipLaunchKernelGGL(fused_lstm, gridA, dim3(256), 0, stream,
          ph0, gin0, gout, o0, whh0, wih1, b1, whd, hbp2, ft, f0);
    }

    if (!bigws) {
      // fallback: standalone gates1 GEMM into the single gate buffer
      hipLaunchKernelGGL(gemm_nt, dim3(32, 32), dim3(256), 0, stream,
          out0, 1024, Wih1, 1024, (float*)gates, 0, 4096, 4096, 1024,
          b1sum, (const float*)nullptr, 0, 1);
    }

    // COOP B: lstm layer1 + fused heads GEMM (flag-gated)
    const dim3 gridB(bigws ? 160 : 128);
    void* args1[] = {&ph1, &gin1, &gout, &o1, &whh1, &wih1, &b1, &whd, &hbp2,
                     &ft, &f1};
    if (hipLaunchCooperativeKernel(reinterpret_cast<void*>(&fused_lstm),
                                   gridB, dim3(256), args1, 0, stream)
        != hipSuccess) {
      hipLaunchKernelGGL(fused_lstm, gridB, dim3(256), 0, stream,
          ph1, gin1, gout, o1, whh1, wih1, b1, whd, hbp2, ft, f1);
    }

    if (!bigws) {
      // fallback: standalone heads GEMM
      hipLaunchKernelGGL(gemm_nt, dim3(1, 32), dim3(256), 0, stream,
          out1, 1024, Wheads, 1024, feat, 96, 4096, 96, 1024,
          hb, (const float*)nullptr, 0, 0);
    }
  }

  hipLaunchKernelGGL(crf_kernel, dim3(64), dim3(256), 0, stream,
      feat, labp, labm, stp, enp, trp, stm, enm, trm, dout);
}

// Round 6
// 882.259 us; speedup vs baseline: 1.8547x; 1.3536x over previous
//
#include <hip/hip_runtime.h>

// ---------------------------------------------------------------------------
// BiLSTM-CRF forward loss on MI355X (gfx950).
// R13: revert to the proven R7 serial structure (R10-R12 showed co-resident
// GEMM producers inflate the lstm handoff latency: fusion is net-negative on
// this dependence structure). Local optimizations only:
//   - gemm_nt staging via __builtin_amdgcn_global_load_lds (16B), with the
//     XOR swizzle baked into the per-lane SOURCE chunk index (LDS dest must
//     be linear: wave-uniform base + lane*16).
//   - sentinel memsets folded into prep_kernel (-2 dispatches).
//   - lstm_rec / CRF / layouts byte-identical to R7.
// Chain: prep -> bert GEMM -> gates0 GEMM -> coop lstm L0 -> gates1 GEMM
//        -> coop lstm L1 -> heads GEMM -> CRF.
// ---------------------------------------------------------------------------

typedef unsigned short u16;
typedef unsigned int u32;
typedef unsigned long long u64;
typedef __attribute__((ext_vector_type(8))) __bf16 bf16x8;
typedef __attribute__((ext_vector_type(4))) float floatx4;

typedef const __attribute__((address_space(1))) u32 gu32;
typedef __attribute__((address_space(3))) u32 lu32;

static __device__ __forceinline__ u16 f2bf(float f) {
  u32 u = __float_as_uint(f);
  u += 0x7fffu + ((u >> 16) & 1u);   // round-to-nearest-even
  return (u16)(u >> 16);
}
static __device__ __forceinline__ float bf2f(u32 bits) {
  return __uint_as_float(bits << 16);
}
static __device__ __forceinline__ float sigf(float x) {
  return 1.0f / (1.0f + __expf(-x));
}
static __device__ __forceinline__ float tanh_(float x) {
  return 1.0f - 2.0f / (1.0f + __expf(2.0f * x));
}
static __device__ __forceinline__ floatx4 mfma16(bf16x8 a, bf16x8 b, floatx4 c) {
  return __builtin_amdgcn_mfma_f32_16x16x32_bf16(a, b, c, 0, 0, 0);
}
static __device__ __forceinline__ u64 aload64(const u64* p) {
  return __hip_atomic_load((u64*)p, __ATOMIC_RELAXED, __HIP_MEMORY_SCOPE_AGENT);
}
static __device__ __forceinline__ void astore64(u64* p, u64 v) {
  __hip_atomic_store(p, v, __ATOMIC_RELAXED, __HIP_MEMORY_SCOPE_AGENT);
}
// async 16B global->LDS: lds dest = base + lane*16 (base wave-uniform)
static __device__ __forceinline__ void gload16(const u16* g, u16* lds_base) {
  __builtin_amdgcn_global_load_lds((gu32*)g, (lu32*)lds_base, 16, 0, 0);
}

// ---------------------------------------------------------------------------
// prep: fp32->bf16 conversions + bias sums + zero d_out + sentinel fills
// ---------------------------------------------------------------------------
__global__ __launch_bounds__(256) void prep_kernel(
    const float* __restrict__ w_ih, const float* __restrict__ w_hh,
    const float* __restrict__ b_ih, const float* __restrict__ b_hh,
    const float* __restrict__ src,  const float* __restrict__ bert,
    const float* __restrict__ hwp,  const float* __restrict__ hbp,
    const float* __restrict__ hwm,  const float* __restrict__ hbm,
    u16* __restrict__ Wsrc, u16* __restrict__ Wbert, u16* __restrict__ Wih1,
    u16* __restrict__ Whh,  u16* __restrict__ SrcBf, u16* __restrict__ BertBf,
    u16* __restrict__ Wheads, float* __restrict__ b0sum, float* __restrict__ b1sum,
    float* __restrict__ hb, float* __restrict__ dout,
    u64* __restrict__ out0s, u64* __restrict__ out1s)
{
  const int NA = 4194304;  // w_ih layer0 -> Wsrc (cols 0:256) + Wbert (256:1024)
  const int NB = 4194304;  // w_ih layer1
  const int NC = 4194304;  // w_hh (both layers)
  const int ND = 1048576;  // src
  const int NE = 24576;    // bert
  const int NF = 98304;    // head weights
  const int NG = 8192;     // bias sums
  const int NH = 96;       // head bias
  const int NI = 2097152;  // sentinel u64 fills (out0 + out1)
  const int TOTAL = NA + NB + NC + ND + NE + NF + NG + NH + 1 + NI;
  for (int i = blockIdx.x * 256 + threadIdx.x; i < TOTAL; i += gridDim.x * 256) {
    int x = i;
    if (x < NA) {
      int c = x & 1023, r = x >> 10;          // r = dir*2048 + row
      float v = w_ih[x];
      if (c < 256) Wsrc[r * 256 + c] = f2bf(v);
      else         Wbert[r * 768 + (c - 256)] = f2bf(v);
      continue;
    }
    x -= NA;
    if (x < NB) { Wih1[x] = f2bf(w_ih[NA + x]); continue; }
    x -= NB;
    if (x < NC) { Whh[x] = f2bf(w_hh[x]); continue; }
    x -= NC;
    if (x < ND) { SrcBf[x] = f2bf(src[x]); continue; }
    x -= ND;
    if (x < NE) { BertBf[x] = f2bf(bert[x]); continue; }
    x -= NE;
    if (x < NF) {
      Wheads[x] = f2bf(x < 32768 ? hwp[x] : hwm[x - 32768]);
      continue;
    }
    x -= NF;
    if (x < NG) {
      float v = b_ih[x] + b_hh[x];
      if (x < 4096) b0sum[x] = v; else b1sum[x - 4096] = v;
      continue;
    }
    x -= NG;
    if (x < NH) { hb[x] = (x < 32) ? hbp[x] : hbm[x - 32]; continue; }
    x -= NH;
    if (x == 0) { dout[0] = 0.f; continue; }
    x -= 1;
    // sentinel fill: bf16 0xFFFF = NaN, unreachable for valid h in (-1,1)
    if (x < 1048576) out0s[x] = ~0ULL;
    else             out1s[x - 1048576] = ~0ULL;
  }
}

// ---------------------------------------------------------------------------
// bf16 NT GEMM: acc[m][n] = sum_k A[m][k]*B[n][k] (+bias[n]) (+aux[m%32][n])
// 128x128 tile, BK=64, XOR-swizzled LDS. Staging via global_load_lds: the
// LDS destination is linear (wave base + lane*16); the swizzle is applied by
// permuting the per-lane SOURCE chunk: cc = (idx&7) ^ ((idx>>3)&7).
// mode 0: C fp32. mode 1: bf16 gates, wave-ordered u64 layout (R7-exact).
// ---------------------------------------------------------------------------
__global__ __launch_bounds__(256) void gemm_nt(
    const u16* __restrict__ A, int lda,
    const u16* __restrict__ B, int ldb,
    float* __restrict__ C, int ldc,
    int M, int N, int K,
    const float* __restrict__ bias_n,
    const float* __restrict__ auxBN, int auxld,
    int mode)
{
  __shared__ __align__(16) u16 As[128 * 64];
  __shared__ __align__(16) u16 Bs[128 * 64];
  const int m0 = blockIdx.y * 128, n0 = blockIdx.x * 128;
  const int tid = threadIdx.x;
  const int wv = tid >> 6, ln = tid & 63;
  const int wm = wv & 1, wn = wv >> 1;
  const int q = ln >> 4, l15 = ln & 15;
  floatx4 acc[4][4];
#pragma unroll
  for (int a = 0; a < 4; ++a)
#pragma unroll
    for (int b2 = 0; b2 < 4; ++b2) acc[a][b2] = (floatx4){0.f, 0.f, 0.f, 0.f};

  for (int kk = 0; kk < K; kk += 64) {
    __syncthreads();
#pragma unroll
    for (int j = 0; j < 4; ++j) {
      const int idx = j * 256 + tid;          // linear LDS chunk id (16B units)
      const int r = idx >> 3;                 // tile row
      const int cc = (idx & 7) ^ (r & 7);     // swizzle-corrected source chunk
      // wave-uniform LDS base (u16 elements): chunk (j*256 + wv*64), 8 u16 each
      const int cb = __builtin_amdgcn_readfirstlane((j * 256 + wv * 64) * 8);
      const int ra = min(m0 + r, M - 1);
      gload16(&A[(long)ra * lda + kk + cc * 8], &As[cb]);
      const int rb = min(n0 + r, N - 1);
      gload16(&B[(long)rb * ldb + kk + cc * 8], &Bs[cb]);
    }
    __syncthreads();
#pragma unroll
    for (int ks = 0; ks < 2; ++ks) {
      bf16x8 af[4], bf[4];
#pragma unroll
      for (int im = 0; im < 4; ++im) {
        const int r = wm * 64 + im * 16 + l15;
        const int slot = (ks * 4 + q) ^ (r & 7);
        af[im] = *(const bf16x8*)&As[r * 64 + slot * 8];
      }
#pragma unroll
      for (int jn = 0; jn < 4; ++jn) {
        const int r = wn * 64 + jn * 16 + l15;
        const int slot = (ks * 4 + q) ^ (r & 7);
        bf[jn] = *(const bf16x8*)&Bs[r * 64 + slot * 8];
      }
#pragma unroll
      for (int im = 0; im < 4; ++im)
#pragma unroll
        for (int jn = 0; jn < 4; ++jn)
          acc[im][jn] = mfma16(af[im], bf[jn], acc[im][jn]);
    }
  }
  // epilogue: C/D layout col=lane&15, row=(lane>>4)*4+reg
  if (mode == 0) {
#pragma unroll
    for (int im = 0; im < 4; ++im)
#pragma unroll
      for (int jn = 0; jn < 4; ++jn) {
        const int n = n0 + wn * 64 + jn * 16 + l15;
        if (n < N) {
          const float badd = bias_n ? bias_n[n] : 0.f;
#pragma unroll
          for (int rg = 0; rg < 4; ++rg) {
            const int m = m0 + wm * 64 + im * 16 + q * 4 + rg;
            if (m < M) {
              float v = acc[im][jn][rg] + badd;
              if (auxBN) v += auxBN[(long)(m & 31) * auxld + n];
              C[(long)m * ldc + n] = v;
            }
          }
        }
      }
  } else {
    u64* G = (u64*)C;
#pragma unroll
    for (int im = 0; im < 4; ++im)
#pragma unroll
      for (int jn = 0; jn < 4; ++jn) {
        const int n = n0 + wn * 64 + jn * 16 + l15;
        const int dirsel = n >> 11, nn = n & 2047;
        const int gt = nn >> 9, u = nn & 511;
        const int ub = u >> 4, low = u & 15;
        const int wvl = low >> 2, jl = low & 3;
        const int l15l = gt * 4 + jl;
        const int m = m0 + wm * 64 + im * 16 + q * 4;   // rg=0 row
        const int s = m >> 5, b0 = m & 31;
        const int mh = b0 >> 4, qq = (b0 >> 2) & 3;
        const float badd = bias_n ? bias_n[n] : 0.f;
        u64 pk = 0;
#pragma unroll
        for (int rg = 0; rg < 4; ++rg) {
          float v = acc[im][jn][rg] + badd;
          if (auxBN) v += auxBN[(long)(b0 + rg) * auxld + n];
          pk |= (u64)f2bf(v) << (16 * rg);
        }
        G[(((((long)dirsel * 128 + s) * 2 + mh) * 32 + ub) * 4 + wvl) * 64
          + l15l * 4 + qq] = pk;
      }
  }
}

// ---------------------------------------------------------------------------
// persistent cooperative LSTM recurrence, one layer, both directions.
// 128 blocks x 256 thr: block = (dir, batch-half of 16, 16 hidden units).
// Dataflow sync: out pre-filled with bf16 NaN 0xFFFF; producers store h as
// atomic u64; consumers retry coalesced atomic u64 loads until non-sentinel.
// (R7-exact)
// ---------------------------------------------------------------------------
__global__ __launch_bounds__(256, 1) void lstm_rec(
    const u16* __restrict__ gates,  // wave-ordered, see gemm_nt mode 1
    u16* __restrict__ out,          // [128][32][1024] bf16 (fwd | bwd)
    const u16* __restrict__ whh)    // [2][2048][512] bf16 (this layer)
{
  __shared__ __align__(16) u16 h_lds[16 * 512];
  __shared__ float gsc[4][16][17];
  const int bid = blockIdx.x;
  const int dir = bid >> 6;
  const int mh = (bid >> 5) & 1;
  const int ub = bid & 31;
  const int u0 = ub * 16;
  const int tid = threadIdx.x;
  const int wv = tid >> 6;
  const int ln = tid & 63;
  const int q = ln >> 4, l15 = ln & 15;

  // gate row for this lane's B-frag column n=l15: (n>>2)=gate type, (n&3)=unit
  const int gate_r = (l15 >> 2) * 512 + u0 + wv * 4 + (l15 & 3);

  bf16x8 bfrag[16];
  {
    const u16* wp = whh + ((long)dir * 2048 + gate_r) * 512 + q * 8;
#pragma unroll
    for (int ks = 0; ks < 16; ++ks)
      bfrag[ks] = *(const bf16x8*)(wp + ks * 32);
  }

  float c = 0.f;                       // cell state for (b_glob, j_lane)
  const int b_glob = mh * 16 + l15;    // batch (update phase)

  // wave-ordered gate pointer: stride per s = 2*32*4*64 = 16384 u64
  const u64* gbase = (const u64*)gates
      + ((((long)dir * 128 * 2 + mh) * 32 + ub) * 4 + wv) * 64 + l15 * 4 + q;

  u64 gcur = gbase[(long)(dir ? 127 : 0) * 16384];
  u64 gnext = 0;

  for (int t = 0; t < 128; ++t) {
    const int s = dir ? (127 - t) : t;
    // gate prefetch for t+1: coalesced 512 B per wave, issued before staging
    // so it completes alongside the staging loads; consumed next step.
    if (t < 127) {
      const int sn = dir ? (126 - t) : (t + 1);
      gnext = gbase[(long)sn * 16384];
    }
    floatx4 acc = (floatx4){0.f, 0.f, 0.f, 0.f};
    if (t > 0) {
      // stage h(t-1): 16 rows x 512 cols bf16. Coalesced device-scope u64
      // loads; each u64 = one producer wave's atomic store -> check low u16.
      const int sp = dir ? (s + 1) : (s - 1);
      const u64* ubp = (const u64*)(out + (((long)sp * 32 + mh * 16) * 1024 + (long)dir * 512));
      u64 v8[8];
#pragma unroll
      for (int j = 0; j < 8; ++j) {
        const int idx = j * 256 + tid;           // 2048 u64 chunks
        const int r = idx >> 7, c4 = idx & 127;  // row, u64-within-row
        v8[j] = aload64(ubp + (long)r * 256 + c4);
      }
      while (true) {
        bool bad = false;
#pragma unroll
        for (int j = 0; j < 8; ++j) bad |= ((v8[j] & 0xffffULL) == 0xffffULL);
        if (!bad) break;
#pragma unroll
        for (int j = 0; j < 8; ++j) {
          if ((v8[j] & 0xffffULL) == 0xffffULL) {
            const int idx = j * 256 + tid;
            const int r = idx >> 7, c4 = idx & 127;
            v8[j] = aload64(ubp + (long)r * 256 + c4);
          }
        }
      }
#pragma unroll
      for (int j = 0; j < 8; ++j) {
        const int idx = j * 256 + tid;
        const int r = idx >> 7, c4 = idx & 127;
        const int cc8 = c4 >> 1, hf = c4 & 1;
        *(u64*)&h_lds[r * 512 + ((cc8 ^ (r & 7)) << 3) + (hf << 2)] = v8[j];
      }
      __syncthreads();   // the ONLY barrier per step
      floatx4 acc1 = (floatx4){0.f, 0.f, 0.f, 0.f};
#pragma unroll
      for (int ks = 0; ks < 16; ks += 2) {   // 2 chains to halve dep latency
        const int slot0 = (ks * 4 + q) ^ (l15 & 7);
        bf16x8 a0 = *(const bf16x8*)&h_lds[l15 * 512 + slot0 * 8];
        acc = mfma16(a0, bfrag[ks], acc);
        const int slot1 = ((ks + 1) * 4 + q) ^ (l15 & 7);
        bf16x8 a1 = *(const bf16x8*)&h_lds[l15 * 512 + slot1 * 8];
        acc1 = mfma16(a1, bfrag[ks + 1], acc1);
      }
      acc += acc1;
    }
    // C-frag (row=batch=q*4+rg, col=n=l15) -> wave-local LDS transpose
#pragma unroll
    for (int rg = 0; rg < 4; ++rg)
      gsc[wv][q * 4 + rg][l15] = acc[rg] + bf2f((u32)((gcur >> (16 * rg)) & 0xffffu));
    // gsc[wv] is touched only by wave wv: wave-synchronous, no barrier
    const float gi = gsc[wv][l15][q];
    const float gf = gsc[wv][l15][4 + q];
    const float gg = gsc[wv][l15][8 + q];
    const float go = gsc[wv][l15][12 + q];
    const float iv = sigf(gi), fv = sigf(gf), gv = tanh_(gg), ov = sigf(go);
    c = fv * c + iv * gv;
    const float h = ov * tanh_(c);
    // pack 4 units (quads q=0..3, lanes 16 apart) -> one u64 store by q==0
    const u32 hv = (u32)f2bf(h);
    const u32 p1 = (u32)__shfl_xor((int)hv, 16);
    const u32 lo32 = hv | (p1 << 16);
    const u64 w64 = (u64)lo32 |
                    ((u64)(u32)__shfl_xor((int)lo32, 32) << 32);
    if (q == 0)
      astore64(
          (u64*)&out[((long)s * 32 + b_glob) * 1024 + dir * 512 + u0 + wv * 4],
          w64);
    gcur = gnext;
  }
}

// ---------------------------------------------------------------------------
// CRF: one block per (task, batch). Double-buffered alpha: 1 barrier/step.
// ---------------------------------------------------------------------------
template <int K>
static __device__ void crf_body(const float* __restrict__ feat, int off,
                                const int* __restrict__ labels, int b,
                                const float* __restrict__ start,
                                const float* __restrict__ end_,
                                const float* __restrict__ trans,
                                float* __restrict__ outp,
                                float* transT, float (*alpha)[64],
                                float* red)
{
  const int tid = threadIdx.x;
  for (int i = tid; i < K * K; i += 256) {
    int kk = i / K, kp2 = i % K;
    transT[kp2 * 65 + kk] = trans[i];
  }
  if (tid < K) alpha[0][tid] = start[tid] + feat[b * 96 + off + tid];
  __syncthreads();
  constexpr int Kq = K / 4;
  const int kp = tid >> 2, k4 = tid & 3;
  const bool act = kp < K;
  int p = 0;
  for (int s = 1; s < 128; ++s) {
    float x[Kq];
    float mx = -3e38f;
    if (act) {
      const float* tr = &transT[kp * 65 + k4 * Kq];
      const float* al = &alpha[p][k4 * Kq];
#pragma unroll
      for (int i2 = 0; i2 < Kq; ++i2) { x[i2] = al[i2] + tr[i2]; mx = fmaxf(mx, x[i2]); }
    }
    mx = fmaxf(mx, __shfl_xor(mx, 1));
    mx = fmaxf(mx, __shfl_xor(mx, 2));
    float ss = 0.f;
    if (act) {
#pragma unroll
      for (int i2 = 0; i2 < Kq; ++i2) ss += __expf(x[i2] - mx);
    }
    ss += __shfl_xor(ss, 1);
    ss += __shfl_xor(ss, 2);
    if (act && k4 == 0)
      alpha[p ^ 1][kp] = mx + __logf(ss) + feat[(s * 32 + b) * 96 + off + kp];
    __syncthreads();
    p ^= 1;
  }
  // numerator terms (one per time step)
  if (tid < 128) {
    const int tg = labels[tid * 32 + b];
    float term = feat[(tid * 32 + b) * 96 + off + tg];
    if (tid == 0) term += start[tg];
    else          term += trans[labels[(tid - 1) * 32 + b] * K + tg];
    if (tid == 127) term += end_[tg];
    red[tid] = term;
  }
  __syncthreads();
  if (tid == 0) {
    float num = 0.f;
    for (int i = 0; i < 128; ++i) num += red[i];
    float mx = -3e38f;
    for (int k = 0; k < K; ++k) mx = fmaxf(mx, alpha[p][k] + end_[k]);
    float ss = 0.f;
    for (int k = 0; k < K; ++k) ss += __expf(alpha[p][k] + end_[k] - mx);
    const float den = mx + __logf(ss);
    atomicAdd(outp, den - num);   // loss contribution = -(num - den)
  }
}

__global__ __launch_bounds__(256) void crf_kernel(
    const float* __restrict__ feat,
    const int* __restrict__ labp, const int* __restrict__ labm,
    const float* __restrict__ stp, const float* __restrict__ enp, const float* __restrict__ trp,
    const float* __restrict__ stm, const float* __restrict__ enm, const float* __restrict__ trm,
    float* __restrict__ outp)
{
  __shared__ float transT[64 * 65];
  __shared__ float alpha[2][64];
  __shared__ float red[128];
  const int task = blockIdx.x >> 5, b = blockIdx.x & 31;
  if (task == 0) crf_body<32>(feat, 0,  labp, b, stp, enp, trp, outp, transT, alpha, red);
  else           crf_body<64>(feat, 32, labm, b, stm, enm, trm, outp, transT, alpha, red);
}

// ---------------------------------------------------------------------------
// launch
// ---------------------------------------------------------------------------
extern "C" void kernel_launch(void* const* d_in, const int* in_sizes, int n_in,
                              void* d_out, int out_size, void* d_ws, size_t ws_size,
                              hipStream_t stream) {
  const float* src  = (const float*)d_in[0];
  const float* bert = (const float*)d_in[1];
  const int*   labp = (const int*)d_in[2];
  const int*   labm = (const int*)d_in[3];
  const float* w_ih = (const float*)d_in[4];
  const float* w_hh = (const float*)d_in[5];
  const float* b_ih = (const float*)d_in[6];
  const float* b_hh = (const float*)d_in[7];
  const float* hwp  = (const float*)d_in[8];
  const float* hbp  = (const float*)d_in[9];
  const float* hwm  = (const float*)d_in[10];
  const float* hbm  = (const float*)d_in[11];
  const float* stp  = (const float*)d_in[12];
  const float* enp  = (const float*)d_in[13];
  const float* trp  = (const float*)d_in[14];
  const float* stm  = (const float*)d_in[15];
  const float* enm  = (const float*)d_in[16];
  const float* trm  = (const float*)d_in[17];

  char* ws = (char*)d_ws;
  u16*   Wsrc     = (u16*)(ws + 0);          // 4096x256 bf16
  u16*   Wbert    = (u16*)(ws + 2097152);    // 4096x768 bf16
  u16*   Wih1     = (u16*)(ws + 8388608);    // 4096x1024 bf16
  u16*   Whh      = (u16*)(ws + 16777216);   // [2][2][2048][512] bf16
  u16*   SrcBf    = (u16*)(ws + 25165824);   // 4096x256 bf16
  u16*   BertBf   = (u16*)(ws + 27262976);   // 32x768 bf16
  u16*   Wheads   = (u16*)(ws + 27312128);   // 96x1024 bf16
  float* b0sum    = (float*)(ws + 27508736); // [4096]
  float* b1sum    = (float*)(ws + 27525120); // [4096]
  float* hb       = (float*)(ws + 27541504); // [96]
  float* bertpart = (float*)(ws + 27542272); // [32][4096]
  float* feat     = (float*)(ws + 28066560); // [4096][96]
  u16*   out0     = (u16*)(ws + 29639424);   // [128][32][1024] bf16
  u16*   out1     = (u16*)(ws + 38028032);   // [128][32][1024] bf16
  u16*   gates    = (u16*)(ws + 46416640);   // wave-ordered bf16 (32 MiB)
  float* dout     = (float*)d_out;

  // prep: conversions + bias sums + dout=0 + sentinel fill of out0/out1
  hipLaunchKernelGGL(prep_kernel, dim3(2048), dim3(256), 0, stream,
      w_ih, w_hh, b_ih, b_hh, src, bert, hwp, hbp, hwm, hbm,
      Wsrc, Wbert, Wih1, Whh, SrcBf, BertBf, Wheads, b0sum, b1sum, hb, dout,
      (u64*)out0, (u64*)out1);

  // bert part: [32,768]@[4096,768]^T + (b_ih0+b_hh0) -> bertpart[32][4096]
  hipLaunchKernelGGL(gemm_nt, dim3(32, 1), dim3(256), 0, stream,
      BertBf, 768, Wbert, 768, bertpart, 4096, 32, 4096, 768,
      b0sum, (const float*)nullptr, 0, 0);

  // layer0 input proj: src@Wsrc^T + bertpart -> bf16 gates (wave-ordered)
  hipLaunchKernelGGL(gemm_nt, dim3(32, 32), dim3(256), 0, stream,
      SrcBf, 256, Wsrc, 256, (float*)gates, 0, 4096, 4096, 256,
      (const float*)nullptr, bertpart, 4096, 1);

  {
    const u16* g = gates; u16* o = out0; const u16* wh = Whh;
    void* args[] = {&g, &o, &wh};
    if (hipLaunchCooperativeKernel(reinterpret_cast<void*>(&lstm_rec),
                                   dim3(128), dim3(256), args, 0, stream)
        != hipSuccess) {
      hipLaunchKernelGGL(lstm_rec, dim3(128), dim3(256), 0, stream, g, o, wh);
    }
  }

  // layer1 input proj: out0@Wih1^T + b1sum -> bf16 gates (wave-ordered)
  hipLaunchKernelGGL(gemm_nt, dim3(32, 32), dim3(256), 0, stream,
      out0, 1024, Wih1, 1024, (float*)gates, 0, 4096, 4096, 1024,
      b1sum, (const float*)nullptr, 0, 1);

  {
    const u16* g = gates; u16* o = out1; const u16* wh = Whh + 2L * 2048 * 512;
    void* args[] = {&g, &o, &wh};
    if (hipLaunchCooperativeKernel(reinterpret_cast<void*>(&lstm_rec),
                                   dim3(128), dim3(256), args, 0, stream)
        != hipSuccess) {
      hipLaunchKernelGGL(lstm_rec, dim3(128), dim3(256), 0, stream, g, o, wh);
    }
  }

  // heads: out1@[96,1024]^T + hb -> feat[4096][96]
  hipLaunchKernelGGL(gemm_nt, dim3(1, 32), dim3(256), 0, stream,
      out1, 1024, Wheads, 1024, feat, 96, 4096, 96, 1024,
      hb, (const float*)nullptr, 0, 0);

  hipLaunchKernelGGL(crf_kernel, dim3(64), dim3(256), 0, stream,
      feat, labp, labm, stp, enp, trp, stm, enm, trm, dout);
}

// Round 7
// 872.401 us; speedup vs baseline: 1.8757x; 1.0113x over previous
//
#include <hip/hip_runtime.h>

// ---------------------------------------------------------------------------
// BiLSTM-CRF forward loss on MI355X (gfx950).
// R14: R13 serial structure + local wins:
//   - prep_kernel fully vectorized: float4 loads, packed u64 (4x bf16)
//     stores; 4x fewer grid-stride iterations.
//   - lstm_rec MFMA: 4 independent accumulation chains (was 2) to halve
//     dependent-chain latency on the per-step critical path.
//   - gemm_nt (global_load_lds staging), CRF, layouts: R13-identical.
// Chain: prep -> bert GEMM -> gates0 GEMM -> coop lstm L0 -> gates1 GEMM
//        -> coop lstm L1 -> heads GEMM -> CRF.
// ---------------------------------------------------------------------------

typedef unsigned short u16;
typedef unsigned int u32;
typedef unsigned long long u64;
typedef __attribute__((ext_vector_type(8))) __bf16 bf16x8;
typedef __attribute__((ext_vector_type(4))) float floatx4;

typedef const __attribute__((address_space(1))) u32 gu32;
typedef __attribute__((address_space(3))) u32 lu32;

static __device__ __forceinline__ u16 f2bf(float f) {
  u32 u = __float_as_uint(f);
  u += 0x7fffu + ((u >> 16) & 1u);   // round-to-nearest-even
  return (u16)(u >> 16);
}
static __device__ __forceinline__ u64 pack4(float4 v) {
  return (u64)f2bf(v.x) | ((u64)f2bf(v.y) << 16) |
         ((u64)f2bf(v.z) << 32) | ((u64)f2bf(v.w) << 48);
}
static __device__ __forceinline__ float bf2f(u32 bits) {
  return __uint_as_float(bits << 16);
}
static __device__ __forceinline__ float sigf(float x) {
  return 1.0f / (1.0f + __expf(-x));
}
static __device__ __forceinline__ float tanh_(float x) {
  return 1.0f - 2.0f / (1.0f + __expf(2.0f * x));
}
static __device__ __forceinline__ floatx4 mfma16(bf16x8 a, bf16x8 b, floatx4 c) {
  return __builtin_amdgcn_mfma_f32_16x16x32_bf16(a, b, c, 0, 0, 0);
}
static __device__ __forceinline__ u64 aload64(const u64* p) {
  return __hip_atomic_load((u64*)p, __ATOMIC_RELAXED, __HIP_MEMORY_SCOPE_AGENT);
}
static __device__ __forceinline__ void astore64(u64* p, u64 v) {
  __hip_atomic_store(p, v, __ATOMIC_RELAXED, __HIP_MEMORY_SCOPE_AGENT);
}
// async 16B global->LDS: lds dest = base + lane*16 (base wave-uniform)
static __device__ __forceinline__ void gload16(const u16* g, u16* lds_base) {
  __builtin_amdgcn_global_load_lds((gu32*)g, (lu32*)lds_base, 16, 0, 0);
}

// ---------------------------------------------------------------------------
// prep: vectorized fp32->bf16 conversions + bias sums + d_out=0 + sentinels.
// All section boundaries are %4==0, so a float4 chunk never straddles one.
// ---------------------------------------------------------------------------
__global__ __launch_bounds__(256) void prep_kernel(
    const float* __restrict__ w_ih, const float* __restrict__ w_hh,
    const float* __restrict__ b_ih, const float* __restrict__ b_hh,
    const float* __restrict__ src,  const float* __restrict__ bert,
    const float* __restrict__ hwp,  const float* __restrict__ hbp,
    const float* __restrict__ hwm,  const float* __restrict__ hbm,
    u16* __restrict__ Wsrc, u16* __restrict__ Wbert, u16* __restrict__ Wih1,
    u16* __restrict__ Whh,  u16* __restrict__ SrcBf, u16* __restrict__ BertBf,
    u16* __restrict__ Wheads, float* __restrict__ b0sum, float* __restrict__ b1sum,
    float* __restrict__ hb, float* __restrict__ dout,
    u64* __restrict__ out0s, u64* __restrict__ out1s)
{
  const int A4 = 1048576;  // w_ih layer0 float4s -> Wsrc / Wbert
  const int B4 = 1048576;  // w_ih layer1 -> Wih1
  const int C4 = 1048576;  // w_hh -> Whh
  const int D4 = 262144;   // src -> SrcBf
  const int E4 = 6144;     // bert -> BertBf
  const int F4 = 24576;    // head weights -> Wheads
  const int G4 = 2048;     // bias sums (fp32)
  const int H4 = 24;       // head bias (fp32)
  const int NI = 2097152;  // sentinel u64 fills (out0 + out1)
  const int TOTAL = A4 + B4 + C4 + D4 + E4 + F4 + G4 + H4 + 1 + NI;
  for (int i = blockIdx.x * 256 + threadIdx.x; i < TOTAL; i += gridDim.x * 256) {
    int x = i;
    if (x < A4) {
      const int e = x * 4, c = e & 1023, r = e >> 10;   // r = dir*2048 + row
      const u64 pk = pack4(*(const float4*)&w_ih[e]);
      if (c < 256) *(u64*)&Wsrc[r * 256 + c] = pk;
      else         *(u64*)&Wbert[r * 768 + (c - 256)] = pk;
      continue;
    }
    x -= A4;
    if (x < B4) {
      *(u64*)&Wih1[x * 4] = pack4(*(const float4*)&w_ih[4194304 + x * 4]);
      continue;
    }
    x -= B4;
    if (x < C4) {
      *(u64*)&Whh[x * 4] = pack4(*(const float4*)&w_hh[x * 4]);
      continue;
    }
    x -= C4;
    if (x < D4) {
      *(u64*)&SrcBf[x * 4] = pack4(*(const float4*)&src[x * 4]);
      continue;
    }
    x -= D4;
    if (x < E4) {
      *(u64*)&BertBf[x * 4] = pack4(*(const float4*)&bert[x * 4]);
      continue;
    }
    x -= E4;
    if (x < F4) {
      const int e = x * 4;
      const float4 v = (e < 32768) ? *(const float4*)&hwp[e]
                                   : *(const float4*)&hwm[e - 32768];
      *(u64*)&Wheads[e] = pack4(v);
      continue;
    }
    x -= F4;
    if (x < G4) {
      const int e = x * 4;
      const float4 a = *(const float4*)&b_ih[e];
      const float4 b = *(const float4*)&b_hh[e];
      const float4 v = {a.x + b.x, a.y + b.y, a.z + b.z, a.w + b.w};
      if (e < 4096) *(float4*)&b0sum[e] = v;
      else          *(float4*)&b1sum[e - 4096] = v;
      continue;
    }
    x -= G4;
    if (x < H4) {
      const int e = x * 4;
      const float4 v = (e < 32) ? *(const float4*)&hbp[e]
                                : *(const float4*)&hbm[e - 32];
      *(float4*)&hb[e] = v;
      continue;
    }
    x -= H4;
    if (x == 0) { dout[0] = 0.f; continue; }
    x -= 1;
    // sentinel fill: bf16 0xFFFF = NaN, unreachable for valid h in (-1,1)
    if (x < 1048576) out0s[x] = ~0ULL;
    else             out1s[x - 1048576] = ~0ULL;
  }
}

// ---------------------------------------------------------------------------
// bf16 NT GEMM: acc[m][n] = sum_k A[m][k]*B[n][k] (+bias[n]) (+aux[m%32][n])
// 128x128 tile, BK=64, XOR-swizzled LDS. Staging via global_load_lds: the
// LDS destination is linear (wave base + lane*16); the swizzle is applied by
// permuting the per-lane SOURCE chunk: cc = (idx&7) ^ ((idx>>3)&7).
// mode 0: C fp32. mode 1: bf16 gates, wave-ordered u64 layout (R7-exact).
// ---------------------------------------------------------------------------
__global__ __launch_bounds__(256) void gemm_nt(
    const u16* __restrict__ A, int lda,
    const u16* __restrict__ B, int ldb,
    float* __restrict__ C, int ldc,
    int M, int N, int K,
    const float* __restrict__ bias_n,
    const float* __restrict__ auxBN, int auxld,
    int mode)
{
  __shared__ __align__(16) u16 As[128 * 64];
  __shared__ __align__(16) u16 Bs[128 * 64];
  const int m0 = blockIdx.y * 128, n0 = blockIdx.x * 128;
  const int tid = threadIdx.x;
  const int wv = tid >> 6, ln = tid & 63;
  const int wm = wv & 1, wn = wv >> 1;
  const int q = ln >> 4, l15 = ln & 15;
  floatx4 acc[4][4];
#pragma unroll
  for (int a = 0; a < 4; ++a)
#pragma unroll
    for (int b2 = 0; b2 < 4; ++b2) acc[a][b2] = (floatx4){0.f, 0.f, 0.f, 0.f};

  for (int kk = 0; kk < K; kk += 64) {
    __syncthreads();
#pragma unroll
    for (int j = 0; j < 4; ++j) {
      const int idx = j * 256 + tid;          // linear LDS chunk id (16B units)
      const int r = idx >> 3;                 // tile row
      const int cc = (idx & 7) ^ (r & 7);     // swizzle-corrected source chunk
      // wave-uniform LDS base (u16 elements): chunk (j*256 + wv*64), 8 u16 each
      const int cb = __builtin_amdgcn_readfirstlane((j * 256 + wv * 64) * 8);
      const int ra = min(m0 + r, M - 1);
      gload16(&A[(long)ra * lda + kk + cc * 8], &As[cb]);
      const int rb = min(n0 + r, N - 1);
      gload16(&B[(long)rb * ldb + kk + cc * 8], &Bs[cb]);
    }
    __syncthreads();
#pragma unroll
    for (int ks = 0; ks < 2; ++ks) {
      bf16x8 af[4], bf[4];
#pragma unroll
      for (int im = 0; im < 4; ++im) {
        const int r = wm * 64 + im * 16 + l15;
        const int slot = (ks * 4 + q) ^ (r & 7);
        af[im] = *(const bf16x8*)&As[r * 64 + slot * 8];
      }
#pragma unroll
      for (int jn = 0; jn < 4; ++jn) {
        const int r = wn * 64 + jn * 16 + l15;
        const int slot = (ks * 4 + q) ^ (r & 7);
        bf[jn] = *(const bf16x8*)&Bs[r * 64 + slot * 8];
      }
#pragma unroll
      for (int im = 0; im < 4; ++im)
#pragma unroll
        for (int jn = 0; jn < 4; ++jn)
          acc[im][jn] = mfma16(af[im], bf[jn], acc[im][jn]);
    }
  }
  // epilogue: C/D layout col=lane&15, row=(lane>>4)*4+reg
  if (mode == 0) {
#pragma unroll
    for (int im = 0; im < 4; ++im)
#pragma unroll
      for (int jn = 0; jn < 4; ++jn) {
        const int n = n0 + wn * 64 + jn * 16 + l15;
        if (n < N) {
          const float badd = bias_n ? bias_n[n] : 0.f;
#pragma unroll
          for (int rg = 0; rg < 4; ++rg) {
            const int m = m0 + wm * 64 + im * 16 + q * 4 + rg;
            if (m < M) {
              float v = acc[im][jn][rg] + badd;
              if (auxBN) v += auxBN[(long)(m & 31) * auxld + n];
              C[(long)m * ldc + n] = v;
            }
          }
        }
      }
  } else {
    u64* G = (u64*)C;
#pragma unroll
    for (int im = 0; im < 4; ++im)
#pragma unroll
      for (int jn = 0; jn < 4; ++jn) {
        const int n = n0 + wn * 64 + jn * 16 + l15;
        const int dirsel = n >> 11, nn = n & 2047;
        const int gt = nn >> 9, u = nn & 511;
        const int ub = u >> 4, low = u & 15;
        const int wvl = low >> 2, jl = low & 3;
        const int l15l = gt * 4 + jl;
        const int m = m0 + wm * 64 + im * 16 + q * 4;   // rg=0 row
        const int s = m >> 5, b0 = m & 31;
        const int mh = b0 >> 4, qq = (b0 >> 2) & 3;
        const float badd = bias_n ? bias_n[n] : 0.f;
        u64 pk = 0;
#pragma unroll
        for (int rg = 0; rg < 4; ++rg) {
          float v = acc[im][jn][rg] + badd;
          if (auxBN) v += auxBN[(long)(b0 + rg) * auxld + n];
          pk |= (u64)f2bf(v) << (16 * rg);
        }
        G[(((((long)dirsel * 128 + s) * 2 + mh) * 32 + ub) * 4 + wvl) * 64
          + l15l * 4 + qq] = pk;
      }
  }
}

// ---------------------------------------------------------------------------
// persistent cooperative LSTM recurrence, one layer, both directions.
// 128 blocks x 256 thr: block = (dir, batch-half of 16, 16 hidden units).
// Dataflow sync: out pre-filled with bf16 NaN 0xFFFF; producers store h as
// atomic u64; consumers retry coalesced atomic u64 loads until non-sentinel.
// R14: 4 independent MFMA chains (was 2) to shorten per-step dep latency.
// ---------------------------------------------------------------------------
__global__ __launch_bounds__(256, 1) void lstm_rec(
    const u16* __restrict__ gates,  // wave-ordered, see gemm_nt mode 1
    u16* __restrict__ out,          // [128][32][1024] bf16 (fwd | bwd)
    const u16* __restrict__ whh)    // [2][2048][512] bf16 (this layer)
{
  __shared__ __align__(16) u16 h_lds[16 * 512];
  __shared__ float gsc[4][16][17];
  const int bid = blockIdx.x;
  const int dir = bid >> 6;
  const int mh = (bid >> 5) & 1;
  const int ub = bid & 31;
  const int u0 = ub * 16;
  const int tid = threadIdx.x;
  const int wv = tid >> 6;
  const int ln = tid & 63;
  const int q = ln >> 4, l15 = ln & 15;

  // gate row for this lane's B-frag column n=l15: (n>>2)=gate type, (n&3)=unit
  const int gate_r = (l15 >> 2) * 512 + u0 + wv * 4 + (l15 & 3);

  bf16x8 bfrag[16];
  {
    const u16* wp = whh + ((long)dir * 2048 + gate_r) * 512 + q * 8;
#pragma unroll
    for (int ks = 0; ks < 16; ++ks)
      bfrag[ks] = *(const bf16x8*)(wp + ks * 32);
  }

  float c = 0.f;                       // cell state for (b_glob, j_lane)
  const int b_glob = mh * 16 + l15;    // batch (update phase)

  // wave-ordered gate pointer: stride per s = 2*32*4*64 = 16384 u64
  const u64* gbase = (const u64*)gates
      + ((((long)dir * 128 * 2 + mh) * 32 + ub) * 4 + wv) * 64 + l15 * 4 + q;

  u64 gcur = gbase[(long)(dir ? 127 : 0) * 16384];
  u64 gnext = 0;

  for (int t = 0; t < 128; ++t) {
    const int s = dir ? (127 - t) : t;
    // gate prefetch for t+1: coalesced 512 B per wave, issued before staging
    // so it completes alongside the staging loads; consumed next step.
    if (t < 127) {
      const int sn = dir ? (126 - t) : (t + 1);
      gnext = gbase[(long)sn * 16384];
    }
    floatx4 acc = (floatx4){0.f, 0.f, 0.f, 0.f};
    if (t > 0) {
      // stage h(t-1): 16 rows x 512 cols bf16. Coalesced device-scope u64
      // loads; each u64 = one producer wave's atomic store -> check low u16.
      const int sp = dir ? (s + 1) : (s - 1);
      const u64* ubp = (const u64*)(out + (((long)sp * 32 + mh * 16) * 1024 + (long)dir * 512));
      u64 v8[8];
#pragma unroll
      for (int j = 0; j < 8; ++j) {
        const int idx = j * 256 + tid;           // 2048 u64 chunks
        const int r = idx >> 7, c4 = idx & 127;  // row, u64-within-row
        v8[j] = aload64(ubp + (long)r * 256 + c4);
      }
      while (true) {
        bool bad = false;
#pragma unroll
        for (int j = 0; j < 8; ++j) bad |= ((v8[j] & 0xffffULL) == 0xffffULL);
        if (!bad) break;
#pragma unroll
        for (int j = 0; j < 8; ++j) {
          if ((v8[j] & 0xffffULL) == 0xffffULL) {
            const int idx = j * 256 + tid;
            const int r = idx >> 7, c4 = idx & 127;
            v8[j] = aload64(ubp + (long)r * 256 + c4);
          }
        }
      }
#pragma unroll
      for (int j = 0; j < 8; ++j) {
        const int idx = j * 256 + tid;
        const int r = idx >> 7, c4 = idx & 127;
        const int cc8 = c4 >> 1, hf = c4 & 1;
        *(u64*)&h_lds[r * 512 + ((cc8 ^ (r & 7)) << 3) + (hf << 2)] = v8[j];
      }
      __syncthreads();   // the ONLY barrier per step
      floatx4 acc1 = (floatx4){0.f, 0.f, 0.f, 0.f};
      floatx4 acc2 = (floatx4){0.f, 0.f, 0.f, 0.f};
      floatx4 acc3 = (floatx4){0.f, 0.f, 0.f, 0.f};
#pragma unroll
      for (int ks = 0; ks < 16; ks += 4) {   // 4 chains: 4-deep dep latency
        const int slot0 = (ks * 4 + q) ^ (l15 & 7);
        bf16x8 a0 = *(const bf16x8*)&h_lds[l15 * 512 + slot0 * 8];
        acc = mfma16(a0, bfrag[ks], acc);
        const int slot1 = ((ks + 1) * 4 + q) ^ (l15 & 7);
        bf16x8 a1 = *(const bf16x8*)&h_lds[l15 * 512 + slot1 * 8];
        acc1 = mfma16(a1, bfrag[ks + 1], acc1);
        const int slot2 = ((ks + 2) * 4 + q) ^ (l15 & 7);
        bf16x8 a2 = *(const bf16x8*)&h_lds[l15 * 512 + slot2 * 8];
        acc2 = mfma16(a2, bfrag[ks + 2], acc2);
        const int slot3 = ((ks + 3) * 4 + q) ^ (l15 & 7);
        bf16x8 a3 = *(const bf16x8*)&h_lds[l15 * 512 + slot3 * 8];
        acc3 = mfma16(a3, bfrag[ks + 3], acc3);
      }
      acc += acc1;
      acc2 += acc3;
      acc += acc2;
    }
    // C-frag (row=batch=q*4+rg, col=n=l15) -> wave-local LDS transpose
#pragma unroll
    for (int rg = 0; rg < 4; ++rg)
      gsc[wv][q * 4 + rg][l15] = acc[rg] + bf2f((u32)((gcur >> (16 * rg)) & 0xffffu));
    // gsc[wv] is touched only by wave wv: wave-synchronous, no barrier
    const float gi = gsc[wv][l15][q];
    const float gf = gsc[wv][l15][4 + q];
    const float gg = gsc[wv][l15][8 + q];
    const float go = gsc[wv][l15][12 + q];
    const float iv = sigf(gi), fv = sigf(gf), gv = tanh_(gg), ov = sigf(go);
    c = fv * c + iv * gv;
    const float h = ov * tanh_(c);
    // pack 4 units (quads q=0..3, lanes 16 apart) -> one u64 store by q==0
    const u32 hv = (u32)f2bf(h);
    const u32 p1 = (u32)__shfl_xor((int)hv, 16);
    const u32 lo32 = hv | (p1 << 16);
    const u64 w64 = (u64)lo32 |
                    ((u64)(u32)__shfl_xor((int)lo32, 32) << 32);
    if (q == 0)
      astore64(
          (u64*)&out[((long)s * 32 + b_glob) * 1024 + dir * 512 + u0 + wv * 4],
          w64);
    gcur = gnext;
  }
}

// ---------------------------------------------------------------------------
// CRF: one block per (task, batch). Double-buffered alpha: 1 barrier/step.
// ---------------------------------------------------------------------------
template <int K>
static __device__ void crf_body(const float* __restrict__ feat, int off,
                                const int* __restrict__ labels, int b,
                                const float* __restrict__ start,
                                const float* __restrict__ end_,
                                const float* __restrict__ trans,
                                float* __restrict__ outp,
                                float* transT, float (*alpha)[64],
                                float* red)
{
  const int tid = threadIdx.x;
  for (int i = tid; i < K * K; i += 256) {
    int kk = i / K, kp2 = i % K;
    transT[kp2 * 65 + kk] = trans[i];
  }
  if (tid < K) alpha[0][tid] = start[tid] + feat[b * 96 + off + tid];
  __syncthreads();
  constexpr int Kq = K / 4;
  const int kp = tid >> 2, k4 = tid & 3;
  const bool act = kp < K;
  int p = 0;
  for (int s = 1; s < 128; ++s) {
    float x[Kq];
    float mx = -3e38f;
    if (act) {
      const float* tr = &transT[kp * 65 + k4 * Kq];
      const float* al = &alpha[p][k4 * Kq];
#pragma unroll
      for (int i2 = 0; i2 < Kq; ++i2) { x[i2] = al[i2] + tr[i2]; mx = fmaxf(mx, x[i2]); }
    }
    mx = fmaxf(mx, __shfl_xor(mx, 1));
    mx = fmaxf(mx, __shfl_xor(mx, 2));
    float ss = 0.f;
    if (act) {
#pragma unroll
      for (int i2 = 0; i2 < Kq; ++i2) ss += __expf(x[i2] - mx);
    }
    ss += __shfl_xor(ss, 1);
    ss += __shfl_xor(ss, 2);
    if (act && k4 == 0)
      alpha[p ^ 1][kp] = mx + __logf(ss) + feat[(s * 32 + b) * 96 + off + kp];
    __syncthreads();
    p ^= 1;
  }
  // numerator terms (one per time step)
  if (tid < 128) {
    const int tg = labels[tid * 32 + b];
    float term = feat[(tid * 32 + b) * 96 + off + tg];
    if (tid == 0) term += start[tg];
    else          term += trans[labels[(tid - 1) * 32 + b] * K + tg];
    if (tid == 127) term += end_[tg];
    red[tid] = term;
  }
  __syncthreads();
  if (tid == 0) {
    float num = 0.f;
    for (int i = 0; i < 128; ++i) num += red[i];
    float mx = -3e38f;
    for (int k = 0; k < K; ++k) mx = fmaxf(mx, alpha[p][k] + end_[k]);
    float ss = 0.f;
    for (int k = 0; k < K; ++k) ss += __expf(alpha[p][k] + end_[k] - mx);
    const float den = mx + __logf(ss);
    atomicAdd(outp, den - num);   // loss contribution = -(num - den)
  }
}

__global__ __launch_bounds__(256) void crf_kernel(
    const float* __restrict__ feat,
    const int* __restrict__ labp, const int* __restrict__ labm,
    const float* __restrict__ stp, const float* __restrict__ enp, const float* __restrict__ trp,
    const float* __restrict__ stm, const float* __restrict__ enm, const float* __restrict__ trm,
    float* __restrict__ outp)
{
  __shared__ float transT[64 * 65];
  __shared__ float alpha[2][64];
  __shared__ float red[128];
  const int task = blockIdx.x >> 5, b = blockIdx.x & 31;
  if (task == 0) crf_body<32>(feat, 0,  labp, b, stp, enp, trp, outp, transT, alpha, red);
  else           crf_body<64>(feat, 32, labm, b, stm, enm, trm, outp, transT, alpha, red);
}

// ---------------------------------------------------------------------------
// launch
// ---------------------------------------------------------------------------
extern "C" void kernel_launch(void* const* d_in, const int* in_sizes, int n_in,
                              void* d_out, int out_size, void* d_ws, size_t ws_size,
                              hipStream_t stream) {
  const float* src  = (const float*)d_in[0];
  const float* bert = (const float*)d_in[1];
  const int*   labp = (const int*)d_in[2];
  const int*   labm = (const int*)d_in[3];
  const float* w_ih = (const float*)d_in[4];
  const float* w_hh = (const float*)d_in[5];
  const float* b_ih = (const float*)d_in[6];
  const float* b_hh = (const float*)d_in[7];
  const float* hwp  = (const float*)d_in[8];
  const float* hbp  = (const float*)d_in[9];
  const float* hwm  = (const float*)d_in[10];
  const float* hbm  = (const float*)d_in[11];
  const float* stp  = (const float*)d_in[12];
  const float* enp  = (const float*)d_in[13];
  const float* trp  = (const float*)d_in[14];
  const float* stm  = (const float*)d_in[15];
  const float* enm  = (const float*)d_in[16];
  const float* trm  = (const float*)d_in[17];

  char* ws = (char*)d_ws;
  u16*   Wsrc     = (u16*)(ws + 0);          // 4096x256 bf16
  u16*   Wbert    = (u16*)(ws + 2097152);    // 4096x768 bf16
  u16*   Wih1     = (u16*)(ws + 8388608);    // 4096x1024 bf16
  u16*   Whh      = (u16*)(ws + 16777216);   // [2][2][2048][512] bf16
  u16*   SrcBf    = (u16*)(ws + 25165824);   // 4096x256 bf16
  u16*   BertBf   = (u16*)(ws + 27262976);   // 32x768 bf16
  u16*   Wheads   = (u16*)(ws + 27312128);   // 96x1024 bf16
  float* b0sum    = (float*)(ws + 27508736); // [4096]
  float* b1sum    = (float*)(ws + 27525120); // [4096]
  float* hb       = (float*)(ws + 27541504); // [96]
  float* bertpart = (float*)(ws + 27542272); // [32][4096]
  float* feat     = (float*)(ws + 28066560); // [4096][96]
  u16*   out0     = (u16*)(ws + 29639424);   // [128][32][1024] bf16
  u16*   out1     = (u16*)(ws + 38028032);   // [128][32][1024] bf16
  u16*   gates    = (u16*)(ws + 46416640);   // wave-ordered bf16 (32 MiB)
  float* dout     = (float*)d_out;

  // prep: conversions + bias sums + dout=0 + sentinel fill of out0/out1
  hipLaunchKernelGGL(prep_kernel, dim3(2048), dim3(256), 0, stream,
      w_ih, w_hh, b_ih, b_hh, src, bert, hwp, hbp, hwm, hbm,
      Wsrc, Wbert, Wih1, Whh, SrcBf, BertBf, Wheads, b0sum, b1sum, hb, dout,
      (u64*)out0, (u64*)out1);

  // bert part: [32,768]@[4096,768]^T + (b_ih0+b_hh0) -> bertpart[32][4096]
  hipLaunchKernelGGL(gemm_nt, dim3(32, 1), dim3(256), 0, stream,
      BertBf, 768, Wbert, 768, bertpart, 4096, 32, 4096, 768,
      b0sum, (const float*)nullptr, 0, 0);

  // layer0 input proj: src@Wsrc^T + bertpart -> bf16 gates (wave-ordered)
  hipLaunchKernelGGL(gemm_nt, dim3(32, 32), dim3(256), 0, stream,
      SrcBf, 256, Wsrc, 256, (float*)gates, 0, 4096, 4096, 256,
      (const float*)nullptr, bertpart, 4096, 1);

  {
    const u16* g = gates; u16* o = out0; const u16* wh = Whh;
    void* args[] = {&g, &o, &wh};
    if (hipLaunchCooperativeKernel(reinterpret_cast<void*>(&lstm_rec),
                                   dim3(128), dim3(256), args, 0, stream)
        != hipSuccess) {
      hipLaunchKernelGGL(lstm_rec, dim3(128), dim3(256), 0, stream, g, o, wh);
    }
  }

  // layer1 input proj: out0@Wih1^T + b1sum -> bf16 gates (wave-ordered)
  hipLaunchKernelGGL(gemm_nt, dim3(32, 32), dim3(256), 0, stream,
      out0, 1024, Wih1, 1024, (float*)gates, 0, 4096, 4096, 1024,
      b1sum, (const float*)nullptr, 0, 1);

  {
    const u16* g = gates; u16* o = out1; const u16* wh = Whh + 2L * 2048 * 512;
    void* args[] = {&g, &o, &wh};
    if (hipLaunchCooperativeKernel(reinterpret_cast<void*>(&lstm_rec),
                                   dim3(128), dim3(256), args, 0, stream)
        != hipSuccess) {
      hipLaunchKernelGGL(lstm_rec, dim3(128), dim3(256), 0, stream, g, o, wh);
    }
  }

  // heads: out1@[96,1024]^T + hb -> feat[4096][96]
  hipLaunchKernelGGL(gemm_nt, dim3(1, 32), dim3(256), 0, stream,
      out1, 1024, Wheads, 1024, feat, 96, 4096, 96, 1024,
      hb, (const float*)nullptr, 0, 0);

  hipLaunchKernelGGL(crf_kernel, dim3(64), dim3(256), 0, stream,
      feat, labp, labm, stp, enp, trp, stm, enm, trm, dout);
}